// Round 2
// baseline (835.328 us; speedup 1.0000x reference)
//
#include <hip/hip_runtime.h>
#include <stdint.h>

typedef __bf16 bf16x8 __attribute__((ext_vector_type(8)));
typedef float f32x4 __attribute__((ext_vector_type(4)));

constexpr int NB = 8;      // batch
constexpr int NC = 256;    // channels C
constexpr int NN = 2048;   // sequence N
constexpr int NH = 4;      // heads
constexpr int ND = 64;     // head dim
constexpr int NC2 = 512;   // 2C

__device__ __forceinline__ ushort f2bf(float f) {
  union { float f; uint32_t u; } x; x.f = f;
  return (ushort)((x.u + 0x7FFFu + ((x.u >> 16) & 1u)) >> 16);
}
__device__ __forceinline__ float bf2f(ushort h) {
  union { uint32_t u; float f; } x; x.u = (uint32_t)h << 16;
  return x.f;
}

// ---------------- small prep kernels ----------------

__global__ void k_cast(const float* __restrict__ s, ushort* __restrict__ d, int n) {
  int i = blockIdx.x * 256 + threadIdx.x;
  if (i < n) d[i] = f2bf(s[i]);
}

// Wm with columns permuted to head-major: dst[co][h*64+d] = Wm[co][d*4+h]
__global__ void k_cast_wm_perm(const float* __restrict__ s, ushort* __restrict__ d) {
  int i = blockIdx.x * 256 + threadIdx.x;   // 65536
  int co = i >> 8, j = i & 255;
  int h = j >> 6, dd = j & 63;
  d[i] = f2bf(s[co * NC + dd * NH + h]);
}

// X [b][C][N] f32 -> XT [b][N][C] bf16
__global__ void k_transpose_cast(const float* __restrict__ s, ushort* __restrict__ d) {
  int n = blockIdx.x * 256 + threadIdx.x;
  int c0 = blockIdx.y * 8;
  int b = blockIdx.z;
  const float* p = s + ((size_t)b * NC + c0) * NN + n;
  union { ushort u[8]; uint4 v; } t;
#pragma unroll
  for (int i = 0; i < 8; ++i) t.u[i] = f2bf(p[(size_t)i * NN]);
  *(uint4*)(d + ((size_t)b * NN + n) * NC + c0) = t.v;
}

// q_nat [b][d*4+h][n] bf16 -> qt [(b*4+h)][n][d] bf16
__global__ void k_head_transpose(const ushort* __restrict__ s, ushort* __restrict__ d) {
  int n = blockIdx.x * 256 + threadIdx.x;
  int d0 = blockIdx.y * 8;
  int z = blockIdx.z, b = z >> 2, h = z & 3;
  const ushort* p = s + ((size_t)b * NC + (size_t)d0 * NH + h) * NN + n;
  union { ushort u[8]; uint4 v; } t;
#pragma unroll
  for (int i = 0; i < 8; ++i) t.u[i] = p[(size_t)i * NH * NN];
  *(uint4*)(d + ((size_t)z * NN + n) * ND + d0) = t.v;
}

__global__ void k_bn_finalize(const float* __restrict__ stats, const float* __restrict__ gamma,
                              const float* __restrict__ beta, float4* __restrict__ aff) {
  int c = blockIdx.x * 256 + threadIdx.x;
  if (c >= NC2) return;
  const float inv_n = 1.f / (float)(NB * NN);
  float mu  = stats[c * 2] * inv_n;
  float var = stats[c * 2 + 1] * inv_n - mu * mu;
  float isg = gamma[c] * rsqrtf(var + 1e-5f);
  aff[c] = make_float4(mu, isg, beta[c], 0.f);
}

// ---------------- fused flash attention ----------------
// grid (64 q-tiles, 32 bh). Block = 256 threads (4 waves).
// P (32 x 2048) lives in LDS as bf16; attn written to global exactly once.

__global__ __launch_bounds__(256, 1) void k_attn(
    const ushort* __restrict__ qt, const ushort* __restrict__ kt,
    const ushort* __restrict__ vnat, float* __restrict__ attn,
    ushort* __restrict__ xT) {
  __shared__ ushort Pl[32 * 2056];   // 131584 B, pad 8 -> 2-way bank alias (free)
  __shared__ ushort KVt[128 * 72];   // 18432 B; K phase [128][72], V phase [64][136]
  __shared__ ushort Qt[32 * 72];     // 4608 B
  __shared__ float m_run[32], s_run[32], inv_s[32];
  __shared__ float m_tile[16][32];
  __shared__ float wred[4][32];

  const int tid = threadIdx.x;
  const int lane = tid & 63, w = tid >> 6;
  const int lr = lane & 15, lg = lane >> 4, lk = lg * 8;
  const int r0 = blockIdx.x * 32;
  const int z = blockIdx.y, b = z >> 2, h = z & 3;

  // stage Q once: 32 rows x 64 d
  {
    int off = tid * 8, row = off >> 6, d = off & 63;
    *(uint4*)&Qt[row * 72 + d] = *(const uint4*)(qt + ((size_t)z * NN + r0 + row) * ND + d);
  }
  if (tid < 32) { m_run[tid] = -INFINITY; s_run[tid] = 0.f; }

  // preload K tile 0 into regs
  uint4 kreg[4];
  {
    const ushort* src = kt + (size_t)z * NN * ND;
#pragma unroll
    for (int i = 0; i < 4; ++i) kreg[i] = *(const uint4*)(src + (tid + i * 256) * 8);
  }

  for (int t = 0; t < 16; ++t) {
    __syncthreads();   // KVt free, wred consumed
#pragma unroll
    for (int i = 0; i < 4; ++i) {
      int off = (tid + i * 256) * 8;
      *(uint4*)&KVt[(off >> 6) * 72 + (off & 63)] = kreg[i];
    }
    __syncthreads();   // K tile ready (Q also ready from pre-loop barrier chain)
    if (t < 15) {
      const ushort* src = kt + ((size_t)z * NN + (t + 1) * 128) * ND;
#pragma unroll
      for (int i = 0; i < 4; ++i) kreg[i] = *(const uint4*)(src + (tid + i * 256) * 8);
    }
    // S tile: 32 rows x 128 cols; wave w owns cols [w*32, w*32+32)
    f32x4 sa[2][2] = {};
#pragma unroll
    for (int ks = 0; ks < 2; ++ks) {
      bf16x8 af[2], bfv[2];
      af[0]  = *(const bf16x8*)&Qt[lr * 72 + ks * 32 + lk];
      af[1]  = *(const bf16x8*)&Qt[(16 + lr) * 72 + ks * 32 + lk];
      bfv[0] = *(const bf16x8*)&KVt[(w * 32 + lr) * 72 + ks * 32 + lk];
      bfv[1] = *(const bf16x8*)&KVt[(w * 32 + 16 + lr) * 72 + ks * 32 + lk];
#pragma unroll
      for (int fr = 0; fr < 2; ++fr)
#pragma unroll
        for (int fc = 0; fc < 2; ++fc)
          sa[fr][fc] = __builtin_amdgcn_mfma_f32_16x16x32_bf16(af[fr], bfv[fc], sa[fr][fc], 0, 0, 0);
    }
    // scale + per-row tile max (reduce over 16-lane col group)
    float rmax[2][4];
#pragma unroll
    for (int fr = 0; fr < 2; ++fr)
#pragma unroll
      for (int j = 0; j < 4; ++j) {
        sa[fr][0][j] *= 0.125f; sa[fr][1][j] *= 0.125f;
        rmax[fr][j] = fmaxf(sa[fr][0][j], sa[fr][1][j]);
      }
#pragma unroll
    for (int o = 1; o < 16; o <<= 1)
#pragma unroll
      for (int fr = 0; fr < 2; ++fr)
#pragma unroll
        for (int j = 0; j < 4; ++j)
          rmax[fr][j] = fmaxf(rmax[fr][j], __shfl_xor(rmax[fr][j], o));
    if (lr == 0)
#pragma unroll
      for (int fr = 0; fr < 2; ++fr)
#pragma unroll
        for (int j = 0; j < 4; ++j)
          wred[w][fr * 16 + lg * 4 + j] = rmax[fr][j];
    __syncthreads();
    if (tid < 32) {
      float tm = fmaxf(fmaxf(wred[0][tid], wred[1][tid]), fmaxf(wred[2][tid], wred[3][tid]));
      float mo = m_run[tid], mn = fmaxf(mo, tm);
      s_run[tid] *= __expf(mo - mn);
      m_run[tid] = mn;
      m_tile[t][tid] = mn;
    }
    __syncthreads();
    // exp (ref = running max), store bf16 P to LDS, per-row partial sums
    float rsum[2][4];
#pragma unroll
    for (int fr = 0; fr < 2; ++fr)
#pragma unroll
      for (int j = 0; j < 4; ++j) {
        int row = fr * 16 + lg * 4 + j;
        float mn = m_tile[t][row];
        float p0 = __expf(sa[fr][0][j] - mn);
        float p1 = __expf(sa[fr][1][j] - mn);
        Pl[row * 2056 + t * 128 + w * 32 + lr]      = f2bf(p0);
        Pl[row * 2056 + t * 128 + w * 32 + 16 + lr] = f2bf(p1);
        rsum[fr][j] = p0 + p1;
      }
#pragma unroll
    for (int o = 1; o < 16; o <<= 1)
#pragma unroll
      for (int fr = 0; fr < 2; ++fr)
#pragma unroll
        for (int j = 0; j < 4; ++j)
          rsum[fr][j] += __shfl_xor(rsum[fr][j], o);
    if (lr == 0)
#pragma unroll
      for (int fr = 0; fr < 2; ++fr)
#pragma unroll
        for (int j = 0; j < 4; ++j)
          wred[w][fr * 16 + lg * 4 + j] = rsum[fr][j];
    __syncthreads();
    if (tid < 32)
      s_run[tid] += wred[0][tid] + wred[1][tid] + wred[2][tid] + wred[3][tid];
  }
  __syncthreads();
  if (tid < 32) inv_s[tid] = 1.f / s_run[tid];
  __syncthreads();

  // normalize sweep: apply exp(m_t - m_fin)/s, write attn once, rewrite P
  {
    int row = tid >> 3, cb = (tid & 7) * 16;
    float* ap = attn + ((size_t)z * NN + r0 + row) * NN;
    float isr = inv_s[row], mf = m_run[row];
#pragma unroll 1
    for (int t = 0; t < 16; ++t) {
      float c_all = __expf(m_tile[t][row] - mf) * isr;
      int base = row * 2056 + t * 128 + cb;
#pragma unroll
      for (int half = 0; half < 2; ++half) {
        union { ushort u[8]; uint4 v; } pv;
        pv.v = *(uint4*)&Pl[base + half * 8];
        float f[8];
#pragma unroll
        for (int e = 0; e < 8; ++e) { f[e] = bf2f(pv.u[e]) * c_all; pv.u[e] = f2bf(f[e]); }
        float* op = ap + t * 128 + cb + half * 8;
        ((float4*)op)[0] = make_float4(f[0], f[1], f[2], f[3]);
        ((float4*)op)[1] = make_float4(f[4], f[5], f[6], f[7]);
        *(uint4*)&Pl[base + half * 8] = pv.v;
      }
    }
  }
  __syncthreads();

  // PV: x(32x64) = P(32x2048) @ V(64x2048)^T-by-rows; wave w owns d in [w*16, w*16+16)
  f32x4 pacc[2] = {};
  uint4 vreg[4];
  {
#pragma unroll
    for (int i = 0; i < 4; ++i) {
      int off = (tid + i * 256) * 8, dd = off >> 7, m = off & 127;
      vreg[i] = *(const uint4*)(vnat + ((size_t)b * NC + dd * 4 + h) * NN + m);
    }
  }
  for (int t = 0; t < 16; ++t) {
#pragma unroll
    for (int i = 0; i < 4; ++i) {
      int off = (tid + i * 256) * 8;
      *(uint4*)&KVt[(off >> 7) * 136 + (off & 127)] = vreg[i];
    }
    __syncthreads();   // V tile ready
    if (t < 15) {
#pragma unroll
      for (int i = 0; i < 4; ++i) {
        int off = (tid + i * 256) * 8, dd = off >> 7, m = off & 127;
        vreg[i] = *(const uint4*)(vnat + ((size_t)b * NC + dd * 4 + h) * NN + (t + 1) * 128 + m);
      }
    }
#pragma unroll
    for (int ks = 0; ks < 4; ++ks) {
      bf16x8 af[2], bfv;
      af[0] = *(const bf16x8*)&Pl[lr * 2056 + t * 128 + ks * 32 + lk];
      af[1] = *(const bf16x8*)&Pl[(16 + lr) * 2056 + t * 128 + ks * 32 + lk];
      bfv   = *(const bf16x8*)&KVt[(w * 16 + lr) * 136 + ks * 32 + lk];
#pragma unroll
      for (int fr = 0; fr < 2; ++fr)
        pacc[fr] = __builtin_amdgcn_mfma_f32_16x16x32_bf16(af[fr], bfv, pacc[fr], 0, 0, 0);
    }
    __syncthreads();   // MFMA done before next V overwrite
  }
  // epilogue: xT[b][n][h*64+d]
#pragma unroll
  for (int fr = 0; fr < 2; ++fr)
#pragma unroll
    for (int j = 0; j < 4; ++j) {
      int n = r0 + fr * 16 + lg * 4 + j;
      xT[((size_t)b * NN + n) * NC + h * 64 + w * 16 + lr] = f2bf(pacc[fr][j]);
    }
}

// ---------------- generic MFMA GEMM: D[r][c] = sum_k A[r][k]*B[c][k] ----------------

enum GemmMode { M_PROJ = 0, M_WM, M_W1, M_W2 };

template <int MODE>
__global__ __launch_bounds__(256) void k_gemm(
    const ushort* __restrict__ A, const ushort* __restrict__ A2,
    const ushort* __restrict__ Bm,
    const float* __restrict__ bias, const float4* __restrict__ aff,
    float* __restrict__ stats, float* __restrict__ outf, ushort* __restrict__ outb) {
  constexpr int BR = 128;
  constexpr int BC = 128;
  constexpr int KT = (MODE == M_PROJ || MODE == M_WM) ? 256 : 512;
  constexpr int FR = 4;
  constexpr int FC = 4;
  constexpr int LDL = 72;

  __shared__ ushort ldsA[BR * LDL];
  __shared__ ushort ldsB[BC * LDL];

  const int tid = threadIdx.x;
  const int lane = tid & 63, wave = tid >> 6;
  const int wr = (wave >> 1) * (FR * 16), wc = (wave & 1) * (FC * 16);
  const int lr = lane & 15, lk = (lane >> 4) * 8;
  const int c0 = blockIdx.x * BC, r0 = blockIdx.y * BR;
  const size_t z = blockIdx.z;

  f32x4 acc[FR][FC] = {};

  for (int kk = 0; kk < KT; kk += 64) {
    // ---- stage A ----
    {
      const ushort* src; int ld;
      if constexpr (MODE == M_PROJ)        { src = A + (size_t)r0 * NC + kk; ld = NC; }
      else if constexpr (MODE == M_WM)     { src = A + (z * NN + r0) * (size_t)NC + kk; ld = NC; }
      else if constexpr (MODE == M_W1) {
        if (kk < NC) src = A  + (z * NN + r0) * (size_t)NC + kk;
        else         src = A2 + (z * NN + r0) * (size_t)NC + (kk - NC);
        ld = NC;
      } else { src = A + (size_t)r0 * NC2 + kk; ld = NC2; }   // M_W2
#pragma unroll
      for (int i = 0; i < BR / 32; ++i) {
        int off = (tid + i * 256) * 8, row = off >> 6, k = off & 63;
        *(uint4*)&ldsA[row * LDL + k] = *(const uint4*)(src + (size_t)row * ld + k);
      }
    }
    // ---- stage B ----
    if constexpr (MODE == M_W2) {
      const ushort* src = Bm + (z * NN + c0) * (size_t)NC2 + kk;
#pragma unroll
      for (int i = 0; i < BC / 32; ++i) {
        int off = (tid + i * 256) * 8, row = off >> 6, k = off & 63;
        union { ushort u[8]; uint4 v; } t, o;
        t.v = *(const uint4*)(src + (size_t)row * NC2 + k);
#pragma unroll
        for (int e = 0; e < 8; ++e) {
          float4 pr = aff[kk + k + e];
          float y = (bf2f(t.u[e]) - pr.x) * pr.y + pr.z;
          y = y > 0.f ? y : 0.2f * y;
          o.u[e] = f2bf(y);
        }
        *(uint4*)&ldsB[row * LDL + k] = o.v;
      }
    } else {
      const ushort* src; int ld;
      if constexpr (MODE == M_PROJ)        { src = Bm + (z * NN + c0) * (size_t)NC + kk; ld = NC; }
      else if constexpr (MODE == M_WM)     { src = Bm + (size_t)c0 * NC + kk; ld = NC; }
      else                                  { src = Bm + (size_t)c0 * NC2 + kk; ld = NC2; }  // M_W1
#pragma unroll
      for (int i = 0; i < BC / 32; ++i) {
        int off = (tid + i * 256) * 8, row = off >> 6, k = off & 63;
        *(uint4*)&ldsB[row * LDL + k] = *(const uint4*)(src + (size_t)row * ld + k);
      }
    }
    __syncthreads();
#pragma unroll
    for (int ks = 0; ks < 2; ++ks) {
      bf16x8 afr[FR], bfr[FC];
#pragma unroll
      for (int fr = 0; fr < FR; ++fr)
        afr[fr] = *(const bf16x8*)&ldsA[(wr + fr * 16 + lr) * LDL + ks * 32 + lk];
#pragma unroll
      for (int fc = 0; fc < FC; ++fc)
        bfr[fc] = *(const bf16x8*)&ldsB[(wc + fc * 16 + lr) * LDL + ks * 32 + lk];
#pragma unroll
      for (int fr = 0; fr < FR; ++fr)
#pragma unroll
        for (int fc = 0; fc < FC; ++fc)
          acc[fr][fc] = __builtin_amdgcn_mfma_f32_16x16x32_bf16(afr[fr], bfr[fc], acc[fr][fc], 0, 0, 0);
    }
    __syncthreads();
  }

  float sfc[FC], qfc[FC];
#pragma unroll
  for (int fc = 0; fc < FC; ++fc) { sfc[fc] = 0.f; qfc[fc] = 0.f; }
#pragma unroll
  for (int fr = 0; fr < FR; ++fr)
#pragma unroll
    for (int fc = 0; fc < FC; ++fc)
#pragma unroll
      for (int j = 0; j < 4; ++j) {
        int r = r0 + wr + fr * 16 + (lane >> 4) * 4 + j;
        int c = c0 + wc + fc * 16 + lr;
        float v = acc[fr][fc][j];
        if constexpr (MODE == M_PROJ) {
          v += bias[r];
          outb[(z * NC + r) * (size_t)NN + c] = f2bf(v);
        } else if constexpr (MODE == M_WM) {
          v += bias[c];
          outb[(z * NN + r) * (size_t)NC + c] = f2bf(v);
        } else if constexpr (MODE == M_W1) {
          v += bias[c];
          outb[(z * NN + r) * (size_t)NC2 + c] = f2bf(v);
          sfc[fc] += v; qfc[fc] += v * v;
        } else {  // M_W2
          v += bias[r];
          outf[(z * NC + r) * (size_t)NN + c] = v;
        }
      }
  if constexpr (MODE == M_W1) {
#pragma unroll
    for (int fc = 0; fc < FC; ++fc) {
      float s1 = sfc[fc], s2 = qfc[fc];
      s1 += __shfl_xor(s1, 16); s1 += __shfl_xor(s1, 32);
      s2 += __shfl_xor(s2, 16); s2 += __shfl_xor(s2, 32);
      if (lane < 16) {
        int ch = c0 + wc + fc * 16 + lane;
        atomicAdd(&stats[ch * 2],     s1);
        atomicAdd(&stats[ch * 2 + 1], s2);
      }
    }
  }
}

// ---------------- launch ----------------

extern "C" void kernel_launch(void* const* d_in, const int* in_sizes, int n_in,
                              void* d_out, int out_size, void* d_ws, size_t ws_size,
                              hipStream_t stream) {
  const float* iq    = (const float*)d_in[0];
  const float* keyi  = (const float*)d_in[1];
  const float* vali  = (const float*)d_in[2];
  const float* Wq = (const float*)d_in[3];  const float* bq = (const float*)d_in[4];
  const float* Wk = (const float*)d_in[5];  const float* bk = (const float*)d_in[6];
  const float* Wv = (const float*)d_in[7];  const float* bv = (const float*)d_in[8];
  const float* Wm = (const float*)d_in[9];  const float* bm = (const float*)d_in[10];
  const float* W1 = (const float*)d_in[11]; const float* b1 = (const float*)d_in[12];
  const float* gamma = (const float*)d_in[13]; const float* beta = (const float*)d_in[14];
  const float* W2 = (const float*)d_in[15]; const float* b2 = (const float*)d_in[16];

  float* out  = (float*)d_out;
  float* attn = out + (size_t)NB * NC * NN;   // [B,H,N,N] f32

  uint8_t* cur = (uint8_t*)d_ws;
  auto alloc = [&](size_t bytes) { uint8_t* p = cur; cur += (bytes + 255) & ~(size_t)255; return p; };
  ushort* wq_b = (ushort*)alloc((size_t)NC * NC * 2);
  ushort* wk_b = (ushort*)alloc((size_t)NC * NC * 2);
  ushort* wv_b = (ushort*)alloc((size_t)NC * NC * 2);
  ushort* wm_b = (ushort*)alloc((size_t)NC * NC * 2);
  ushort* w1_b = (ushort*)alloc((size_t)NC2 * NC2 * 2);
  ushort* w2_b = (ushort*)alloc((size_t)NC * NC2 * 2);
  const size_t TN = (size_t)NB * NN * NC;
  ushort* iqT   = (ushort*)alloc(TN * 2);  // init_query^T  [b][n][c]
  ushort* kT    = (ushort*)alloc(TN * 2);
  ushort* vT    = (ushort*)alloc(TN * 2);
  ushort* q_nat = (ushort*)alloc(TN * 2);  // [b][c][n]
  ushort* k_nat = (ushort*)alloc(TN * 2);
  ushort* v_nat = (ushort*)alloc(TN * 2);
  ushort* qt    = (ushort*)alloc(TN * 2);  // [(b h)][n][d]
  ushort* kt    = (ushort*)alloc(TN * 2);
  ushort* xT    = (ushort*)alloc(TN * 2);  // attn@V, [b][n][h*64+d]
  ushort* xmT   = (ushort*)alloc(TN * 2);  // merge out^T [b][n][co]
  ushort* hT    = (ushort*)alloc((size_t)NB * NN * NC2 * 2);
  float*  stats = (float*)alloc(NC2 * 2 * 4);
  float4* aff   = (float4*)alloc(NC2 * 16);

  hipMemsetAsync(stats, 0, NC2 * 2 * 4, stream);

  k_cast<<<dim3(256), 256, 0, stream>>>(Wq, wq_b, NC * NC);
  k_cast<<<dim3(256), 256, 0, stream>>>(Wk, wk_b, NC * NC);
  k_cast<<<dim3(256), 256, 0, stream>>>(Wv, wv_b, NC * NC);
  k_cast_wm_perm<<<dim3(256), 256, 0, stream>>>(Wm, wm_b);
  k_cast<<<dim3(1024), 256, 0, stream>>>(W1, w1_b, NC2 * NC2);
  k_cast<<<dim3(512), 256, 0, stream>>>(W2, w2_b, NC * NC2);

  k_transpose_cast<<<dim3(8, 32, 8), 256, 0, stream>>>(iq,   iqT);
  k_transpose_cast<<<dim3(8, 32, 8), 256, 0, stream>>>(keyi, kT);
  k_transpose_cast<<<dim3(8, 32, 8), 256, 0, stream>>>(vali, vT);

  k_gemm<M_PROJ><<<dim3(16, 2, 8), 256, 0, stream>>>(wq_b, nullptr, iqT, bq, nullptr, nullptr, nullptr, q_nat);
  k_gemm<M_PROJ><<<dim3(16, 2, 8), 256, 0, stream>>>(wk_b, nullptr, kT,  bk, nullptr, nullptr, nullptr, k_nat);
  k_gemm<M_PROJ><<<dim3(16, 2, 8), 256, 0, stream>>>(wv_b, nullptr, vT,  bv, nullptr, nullptr, nullptr, v_nat);

  k_head_transpose<<<dim3(8, 8, 32), 256, 0, stream>>>(q_nat, qt);
  k_head_transpose<<<dim3(8, 8, 32), 256, 0, stream>>>(k_nat, kt);

  k_attn<<<dim3(64, 32), 256, 0, stream>>>(qt, kt, v_nat, attn, xT);

  k_gemm<M_WM><<<dim3(2, 16, 8), 256, 0, stream>>>(xT, nullptr, wm_b, bm, nullptr, nullptr, nullptr, xmT);

  k_gemm<M_W1><<<dim3(4, 16, 8), 256, 0, stream>>>(xmT, iqT, w1_b, b1, nullptr, stats, nullptr, hT);

  k_bn_finalize<<<dim3(2), 256, 0, stream>>>(stats, gamma, beta, aff);

  k_gemm<M_W2><<<dim3(16, 2, 8), 256, 0, stream>>>(w2_b, nullptr, hT, b2, aff, nullptr, out, nullptr);
}

// Round 3
// 597.831 us; speedup vs baseline: 1.3973x; 1.3973x over previous
//
#include <hip/hip_runtime.h>
#include <stdint.h>

typedef __bf16 bf16x8 __attribute__((ext_vector_type(8)));
typedef float f32x4 __attribute__((ext_vector_type(4)));

constexpr int NB = 8;      // batch
constexpr int NC = 256;    // channels C
constexpr int NN = 2048;   // sequence N
constexpr int NH = 4;      // heads
constexpr int ND = 64;     // head dim
constexpr int NC2 = 512;   // 2C

__device__ __forceinline__ ushort f2bf(float f) {
  union { float f; uint32_t u; } x; x.f = f;
  return (ushort)((x.u + 0x7FFFu + ((x.u >> 16) & 1u)) >> 16);
}
__device__ __forceinline__ float bf2f(ushort h) {
  union { uint32_t u; float f; } x; x.u = (uint32_t)h << 16;
  return x.f;
}

// ---------------- small prep kernels ----------------

__global__ void k_cast(const float* __restrict__ s, ushort* __restrict__ d, int n) {
  int i = blockIdx.x * 256 + threadIdx.x;
  if (i < n) d[i] = f2bf(s[i]);
}

// Wm with columns permuted to head-major: dst[co][h*64+d] = Wm[co][d*4+h]
__global__ void k_cast_wm_perm(const float* __restrict__ s, ushort* __restrict__ d) {
  int i = blockIdx.x * 256 + threadIdx.x;   // 65536
  int co = i >> 8, j = i & 255;
  int h = j >> 6, dd = j & 63;
  d[i] = f2bf(s[co * NC + dd * NH + h]);
}

// X [b][C][N] f32 -> XT [b][N][C] bf16
__global__ void k_transpose_cast(const float* __restrict__ s, ushort* __restrict__ d) {
  int n = blockIdx.x * 256 + threadIdx.x;
  int c0 = blockIdx.y * 8;
  int b = blockIdx.z;
  const float* p = s + ((size_t)b * NC + c0) * NN + n;
  union { ushort u[8]; uint4 v; } t;
#pragma unroll
  for (int i = 0; i < 8; ++i) t.u[i] = f2bf(p[(size_t)i * NN]);
  *(uint4*)(d + ((size_t)b * NN + n) * NC + c0) = t.v;
}

// k_nat [b][d*4+h][n] bf16 -> kt [(b*4+h)][n][d] bf16
__global__ void k_head_transpose(const ushort* __restrict__ s, ushort* __restrict__ d) {
  int n = blockIdx.x * 256 + threadIdx.x;
  int d0 = blockIdx.y * 8;
  int z = blockIdx.z, b = z >> 2, h = z & 3;
  const ushort* p = s + ((size_t)b * NC + (size_t)d0 * NH + h) * NN + n;
  union { ushort u[8]; uint4 v; } t;
#pragma unroll
  for (int i = 0; i < 8; ++i) t.u[i] = p[(size_t)i * NH * NN];
  *(uint4*)(d + ((size_t)z * NN + n) * ND + d0) = t.v;
}

__global__ void k_bn_finalize(const float* __restrict__ stats, const float* __restrict__ gamma,
                              const float* __restrict__ beta, float4* __restrict__ aff) {
  int c = blockIdx.x * 256 + threadIdx.x;
  if (c >= NC2) return;
  const float inv_n = 1.f / (float)(NB * NN);
  float mu  = stats[c * 2] * inv_n;
  float var = stats[c * 2 + 1] * inv_n - mu * mu;
  float isg = gamma[c] * rsqrtf(var + 1e-5f);
  aff[c] = make_float4(mu, isg, beta[c], 0.f);
}

// ---------------- fused flash attention (recompute, barrier-free) ----------------
// 1024 blocks = 8 XCD x 4 bh x 32 q-strips of 64 rows. 256 thr = 4 waves;
// wave w owns q-rows [w*16, w*16+16). K/V fragments read straight from
// global (L2-resident per (b,h)); only P round-trips an 8 KB swizzled LDS.

__global__ __launch_bounds__(256, 4) void k_attn(
    const ushort* __restrict__ q_nat, const ushort* __restrict__ kt,
    const ushort* __restrict__ vnat, float* __restrict__ attn,
    ushort* __restrict__ xT) {
  __shared__ ushort Pl[64 * 64];   // [row][col] bf16, byte ^= (row&7)<<4

  const int tid = threadIdx.x;
  const int lane = tid & 63, w = tid >> 6;
  const int lr = lane & 15, lg = lane >> 4;

  int flat = blockIdx.x;
  int xcd = flat & 7, idx = flat >> 3;
  int z = xcd * 4 + (idx >> 5);       // bh index: 4 per XCD -> K/V L2-resident
  int r0 = (idx & 31) * 64;
  int b = z >> 2, h = z & 3;

  // preload Q A-fragments (rows w*16+lr) from q_nat [b][d*4+h][n]
  bf16x8 aq[2];
  {
    int qrow = r0 + w * 16 + lr;
#pragma unroll
    for (int ks = 0; ks < 2; ++ks) {
      union { ushort u[8]; bf16x8 v; } t;
#pragma unroll
      for (int e = 0; e < 8; ++e) {
        int d = ks * 32 + lg * 8 + e;
        t.u[e] = q_nat[((size_t)b * NC + d * 4 + h) * NN + qrow];
      }
      aq[ks] = t.v;
    }
  }

  const ushort* kbase = kt + (size_t)z * NN * ND;
  const ushort* vbase = vnat + ((size_t)b * NC + h) * NN;

  float m_run[4], s_run[4];
#pragma unroll
  for (int j = 0; j < 4; ++j) { m_run[j] = -INFINITY; s_run[j] = 0.f; }

  // ---- pass 1: online row max / sum (registers only, no barriers) ----
  for (int t = 0; t < 32; ++t) {
    f32x4 sa[4] = {};
#pragma unroll
    for (int ks = 0; ks < 2; ++ks)
#pragma unroll
      for (int fc = 0; fc < 4; ++fc) {
        bf16x8 bk = *(const bf16x8*)(kbase + ((size_t)t * 64 + fc * 16 + lr) * ND + ks * 32 + lg * 8);
        sa[fc] = __builtin_amdgcn_mfma_f32_16x16x32_bf16(aq[ks], bk, sa[fc], 0, 0, 0);
      }
#pragma unroll
    for (int fc = 0; fc < 4; ++fc)
#pragma unroll
      for (int j = 0; j < 4; ++j) sa[fc][j] *= 0.125f;
    float tm[4], es[4];
#pragma unroll
    for (int j = 0; j < 4; ++j)
      tm[j] = fmaxf(fmaxf(sa[0][j], sa[1][j]), fmaxf(sa[2][j], sa[3][j]));
#pragma unroll
    for (int o = 1; o < 16; o <<= 1)
#pragma unroll
      for (int j = 0; j < 4; ++j) tm[j] = fmaxf(tm[j], __shfl_xor(tm[j], o));
#pragma unroll
    for (int j = 0; j < 4; ++j) {
      float mn = fmaxf(m_run[j], tm[j]);
      es[j] = __expf(sa[0][j] - mn) + __expf(sa[1][j] - mn)
            + __expf(sa[2][j] - mn) + __expf(sa[3][j] - mn);
      float corr = __expf(m_run[j] - mn);
      s_run[j] *= corr;
      m_run[j] = mn;
    }
#pragma unroll
    for (int o = 1; o < 16; o <<= 1)
#pragma unroll
      for (int j = 0; j < 4; ++j) es[j] += __shfl_xor(es[j], o);
#pragma unroll
    for (int j = 0; j < 4; ++j) s_run[j] += es[j];
  }

  float inv_s[4];
#pragma unroll
  for (int j = 0; j < 4; ++j) inv_s[j] = 1.f / s_run[j];

  // ---- pass 2: recompute S, write normalized attn once, PV via LDS P-tile ----
  f32x4 acc[4] = {};
  const int prow = w * 16 + lr;
  char* plb = (char*)Pl;
  for (int t = 0; t < 32; ++t) {
    f32x4 sa[4] = {};
#pragma unroll
    for (int ks = 0; ks < 2; ++ks)
#pragma unroll
      for (int fc = 0; fc < 4; ++fc) {
        bf16x8 bk = *(const bf16x8*)(kbase + ((size_t)t * 64 + fc * 16 + lr) * ND + ks * 32 + lg * 8);
        sa[fc] = __builtin_amdgcn_mfma_f32_16x16x32_bf16(aq[ks], bk, sa[fc], 0, 0, 0);
      }
    float* abase = attn + ((size_t)z * NN + r0) * NN + t * 64;
#pragma unroll
    for (int fc = 0; fc < 4; ++fc)
#pragma unroll
      for (int j = 0; j < 4; ++j) {
        int row = w * 16 + lg * 4 + j;
        float p = __expf(sa[fc][j] * 0.125f - m_run[j]) * inv_s[j];
        abase[(size_t)row * NN + fc * 16 + lr] = p;
        int byte = (row << 7) + ((fc * 16 + lr) << 1);
        byte ^= (row & 7) << 4;
        *(ushort*)(plb + byte) = f2bf(p);
      }
#pragma unroll
    for (int ks = 0; ks < 2; ++ks) {
      int abyte = (prow << 7) + ks * 64 + lg * 16;
      abyte ^= (prow & 7) << 4;
      bf16x8 ap = *(const bf16x8*)(plb + abyte);
#pragma unroll
      for (int fc = 0; fc < 4; ++fc) {
        bf16x8 bv = *(const bf16x8*)(vbase + (size_t)(fc * 16 + lr) * 4 * NN + t * 64 + ks * 32 + lg * 8);
        acc[fc] = __builtin_amdgcn_mfma_f32_16x16x32_bf16(ap, bv, acc[fc], 0, 0, 0);
      }
    }
  }
  // epilogue: xT[b][n][h*64+d]
#pragma unroll
  for (int fc = 0; fc < 4; ++fc)
#pragma unroll
    for (int j = 0; j < 4; ++j) {
      int n = r0 + w * 16 + lg * 4 + j;
      xT[((size_t)b * NN + n) * NC + h * 64 + fc * 16 + lr] = f2bf(acc[fc][j]);
    }
}

// ---------------- generic MFMA GEMM: D[r][c] = sum_k A[r][k]*B[c][k] ----------------

enum GemmMode { M_PROJ = 0, M_WM, M_W1, M_W2 };

template <int MODE>
__global__ __launch_bounds__(256) void k_gemm(
    const ushort* __restrict__ A, const ushort* __restrict__ A2,
    const ushort* __restrict__ Bm,
    const float* __restrict__ bias, const float4* __restrict__ aff,
    float* __restrict__ stats, float* __restrict__ outf, ushort* __restrict__ outb) {
  constexpr int BR = 128;
  constexpr int BC = 128;
  constexpr int KT = (MODE == M_PROJ || MODE == M_WM) ? 256 : 512;
  constexpr int FR = 4;
  constexpr int FC = 4;
  constexpr int LDL = 72;

  __shared__ ushort ldsA[BR * LDL];
  __shared__ ushort ldsB[BC * LDL];

  const int tid = threadIdx.x;
  const int lane = tid & 63, wave = tid >> 6;
  const int wr = (wave >> 1) * (FR * 16), wc = (wave & 1) * (FC * 16);
  const int lr = lane & 15, lk = (lane >> 4) * 8;
  const int c0 = blockIdx.x * BC, r0 = blockIdx.y * BR;
  const size_t z = blockIdx.z;

  f32x4 acc[FR][FC] = {};

  for (int kk = 0; kk < KT; kk += 64) {
    // ---- stage A ----
    {
      const ushort* src; int ld;
      if constexpr (MODE == M_PROJ)        { src = A + (size_t)r0 * NC + kk; ld = NC; }
      else if constexpr (MODE == M_WM)     { src = A + (z * NN + r0) * (size_t)NC + kk; ld = NC; }
      else if constexpr (MODE == M_W1) {
        if (kk < NC) src = A  + (z * NN + r0) * (size_t)NC + kk;
        else         src = A2 + (z * NN + r0) * (size_t)NC + (kk - NC);
        ld = NC;
      } else { src = A + (size_t)r0 * NC2 + kk; ld = NC2; }   // M_W2
#pragma unroll
      for (int i = 0; i < BR / 32; ++i) {
        int off = (tid + i * 256) * 8, row = off >> 6, k = off & 63;
        *(uint4*)&ldsA[row * LDL + k] = *(const uint4*)(src + (size_t)row * ld + k);
      }
    }
    // ---- stage B ----
    if constexpr (MODE == M_W2) {
      const ushort* src = Bm + (z * NN + c0) * (size_t)NC2 + kk;
#pragma unroll
      for (int i = 0; i < BC / 32; ++i) {
        int off = (tid + i * 256) * 8, row = off >> 6, k = off & 63;
        union { ushort u[8]; uint4 v; } t, o;
        t.v = *(const uint4*)(src + (size_t)row * NC2 + k);
#pragma unroll
        for (int e = 0; e < 8; ++e) {
          float4 pr = aff[kk + k + e];
          float y = (bf2f(t.u[e]) - pr.x) * pr.y + pr.z;
          y = y > 0.f ? y : 0.2f * y;
          o.u[e] = f2bf(y);
        }
        *(uint4*)&ldsB[row * LDL + k] = o.v;
      }
    } else {
      const ushort* src; int ld;
      if constexpr (MODE == M_PROJ)        { src = Bm + (z * NN + c0) * (size_t)NC + kk; ld = NC; }
      else if constexpr (MODE == M_WM)     { src = Bm + (size_t)c0 * NC + kk; ld = NC; }
      else                                  { src = Bm + (size_t)c0 * NC2 + kk; ld = NC2; }  // M_W1
#pragma unroll
      for (int i = 0; i < BC / 32; ++i) {
        int off = (tid + i * 256) * 8, row = off >> 6, k = off & 63;
        *(uint4*)&ldsB[row * LDL + k] = *(const uint4*)(src + (size_t)row * ld + k);
      }
    }
    __syncthreads();
#pragma unroll
    for (int ks = 0; ks < 2; ++ks) {
      bf16x8 afr[FR], bfr[FC];
#pragma unroll
      for (int fr = 0; fr < FR; ++fr)
        afr[fr] = *(const bf16x8*)&ldsA[(wr + fr * 16 + lr) * LDL + ks * 32 + lk];
#pragma unroll
      for (int fc = 0; fc < FC; ++fc)
        bfr[fc] = *(const bf16x8*)&ldsB[(wc + fc * 16 + lr) * LDL + ks * 32 + lk];
#pragma unroll
      for (int fr = 0; fr < FR; ++fr)
#pragma unroll
        for (int fc = 0; fc < FC; ++fc)
          acc[fr][fc] = __builtin_amdgcn_mfma_f32_16x16x32_bf16(afr[fr], bfr[fc], acc[fr][fc], 0, 0, 0);
    }
    __syncthreads();
  }

  float sfc[FC], qfc[FC];
#pragma unroll
  for (int fc = 0; fc < FC; ++fc) { sfc[fc] = 0.f; qfc[fc] = 0.f; }
#pragma unroll
  for (int fr = 0; fr < FR; ++fr)
#pragma unroll
    for (int fc = 0; fc < FC; ++fc)
#pragma unroll
      for (int j = 0; j < 4; ++j) {
        int r = r0 + wr + fr * 16 + (lane >> 4) * 4 + j;
        int c = c0 + wc + fc * 16 + lr;
        float v = acc[fr][fc][j];
        if constexpr (MODE == M_PROJ) {
          v += bias[r];
          outb[(z * NC + r) * (size_t)NN + c] = f2bf(v);
        } else if constexpr (MODE == M_WM) {
          v += bias[c];
          outb[(z * NN + r) * (size_t)NC + c] = f2bf(v);
        } else if constexpr (MODE == M_W1) {
          v += bias[c];
          outb[(z * NN + r) * (size_t)NC2 + c] = f2bf(v);
          sfc[fc] += v; qfc[fc] += v * v;
        } else {  // M_W2
          v += bias[r];
          outf[(z * NC + r) * (size_t)NN + c] = v;
        }
      }
  if constexpr (MODE == M_W1) {
#pragma unroll
    for (int fc = 0; fc < FC; ++fc) {
      float s1 = sfc[fc], s2 = qfc[fc];
      s1 += __shfl_xor(s1, 16); s1 += __shfl_xor(s1, 32);
      s2 += __shfl_xor(s2, 16); s2 += __shfl_xor(s2, 32);
      if (lane < 16) {
        int ch = c0 + wc + fc * 16 + lane;
        atomicAdd(&stats[ch * 2],     s1);
        atomicAdd(&stats[ch * 2 + 1], s2);
      }
    }
  }
}

// ---------------- launch ----------------

extern "C" void kernel_launch(void* const* d_in, const int* in_sizes, int n_in,
                              void* d_out, int out_size, void* d_ws, size_t ws_size,
                              hipStream_t stream) {
  const float* iq    = (const float*)d_in[0];
  const float* keyi  = (const float*)d_in[1];
  const float* vali  = (const float*)d_in[2];
  const float* Wq = (const float*)d_in[3];  const float* bq = (const float*)d_in[4];
  const float* Wk = (const float*)d_in[5];  const float* bk = (const float*)d_in[6];
  const float* Wv = (const float*)d_in[7];  const float* bv = (const float*)d_in[8];
  const float* Wm = (const float*)d_in[9];  const float* bm = (const float*)d_in[10];
  const float* W1 = (const float*)d_in[11]; const float* b1 = (const float*)d_in[12];
  const float* gamma = (const float*)d_in[13]; const float* beta = (const float*)d_in[14];
  const float* W2 = (const float*)d_in[15]; const float* b2 = (const float*)d_in[16];

  float* out  = (float*)d_out;
  float* attn = out + (size_t)NB * NC * NN;   // [B,H,N,N] f32

  uint8_t* cur = (uint8_t*)d_ws;
  auto alloc = [&](size_t bytes) { uint8_t* p = cur; cur += (bytes + 255) & ~(size_t)255; return p; };
  ushort* wq_b = (ushort*)alloc((size_t)NC * NC * 2);
  ushort* wk_b = (ushort*)alloc((size_t)NC * NC * 2);
  ushort* wv_b = (ushort*)alloc((size_t)NC * NC * 2);
  ushort* wm_b = (ushort*)alloc((size_t)NC * NC * 2);
  ushort* w1_b = (ushort*)alloc((size_t)NC2 * NC2 * 2);
  ushort* w2_b = (ushort*)alloc((size_t)NC * NC2 * 2);
  const size_t TN = (size_t)NB * NN * NC;
  ushort* iqT   = (ushort*)alloc(TN * 2);  // init_query^T  [b][n][c]
  ushort* kT    = (ushort*)alloc(TN * 2);
  ushort* vT    = (ushort*)alloc(TN * 2);
  ushort* q_nat = (ushort*)alloc(TN * 2);  // [b][c][n]
  ushort* k_nat = (ushort*)alloc(TN * 2);
  ushort* v_nat = (ushort*)alloc(TN * 2);
  ushort* kt    = (ushort*)alloc(TN * 2);  // [(b h)][n][d]
  ushort* xT    = (ushort*)alloc(TN * 2);  // attn@V, [b][n][h*64+d]
  ushort* xmT   = (ushort*)alloc(TN * 2);  // merge out^T [b][n][co]
  ushort* hT    = (ushort*)alloc((size_t)NB * NN * NC2 * 2);
  float*  stats = (float*)alloc(NC2 * 2 * 4);
  float4* aff   = (float4*)alloc(NC2 * 16);

  hipMemsetAsync(stats, 0, NC2 * 2 * 4, stream);

  k_cast<<<dim3(256), 256, 0, stream>>>(Wq, wq_b, NC * NC);
  k_cast<<<dim3(256), 256, 0, stream>>>(Wk, wk_b, NC * NC);
  k_cast<<<dim3(256), 256, 0, stream>>>(Wv, wv_b, NC * NC);
  k_cast_wm_perm<<<dim3(256), 256, 0, stream>>>(Wm, wm_b);
  k_cast<<<dim3(1024), 256, 0, stream>>>(W1, w1_b, NC2 * NC2);
  k_cast<<<dim3(512), 256, 0, stream>>>(W2, w2_b, NC * NC2);

  k_transpose_cast<<<dim3(8, 32, 8), 256, 0, stream>>>(iq,   iqT);
  k_transpose_cast<<<dim3(8, 32, 8), 256, 0, stream>>>(keyi, kT);
  k_transpose_cast<<<dim3(8, 32, 8), 256, 0, stream>>>(vali, vT);

  k_gemm<M_PROJ><<<dim3(16, 2, 8), 256, 0, stream>>>(wq_b, nullptr, iqT, bq, nullptr, nullptr, nullptr, q_nat);
  k_gemm<M_PROJ><<<dim3(16, 2, 8), 256, 0, stream>>>(wk_b, nullptr, kT,  bk, nullptr, nullptr, nullptr, k_nat);
  k_gemm<M_PROJ><<<dim3(16, 2, 8), 256, 0, stream>>>(wv_b, nullptr, vT,  bv, nullptr, nullptr, nullptr, v_nat);

  k_head_transpose<<<dim3(8, 8, 32), 256, 0, stream>>>(k_nat, kt);

  k_attn<<<dim3(1024), 256, 0, stream>>>(q_nat, kt, v_nat, attn, xT);

  k_gemm<M_WM><<<dim3(2, 16, 8), 256, 0, stream>>>(xT, nullptr, wm_b, bm, nullptr, nullptr, nullptr, xmT);

  k_gemm<M_W1><<<dim3(4, 16, 8), 256, 0, stream>>>(xmT, iqT, w1_b, b1, nullptr, stats, nullptr, hT);

  k_bn_finalize<<<dim3(2), 256, 0, stream>>>(stats, gamma, beta, aff);

  k_gemm<M_W2><<<dim3(16, 2, 8), 256, 0, stream>>>(w2_b, nullptr, hT, b2, aff, nullptr, out, nullptr);
}

// Round 5
// 522.393 us; speedup vs baseline: 1.5990x; 1.1444x over previous
//
#include <hip/hip_runtime.h>
#include <stdint.h>

typedef __bf16 bf16x8 __attribute__((ext_vector_type(8)));
typedef float f32x4 __attribute__((ext_vector_type(4)));

constexpr int NB = 8;      // batch
constexpr int NC = 256;    // channels C
constexpr int NN = 2048;   // sequence N
constexpr int NH = 4;      // heads
constexpr int ND = 64;     // head dim
constexpr int NC2 = 512;   // 2C

__device__ __forceinline__ ushort f2bf(float f) {
  union { float f; uint32_t u; } x; x.f = f;
  return (ushort)((x.u + 0x7FFFu + ((x.u >> 16) & 1u)) >> 16);
}
__device__ __forceinline__ float bf2f(ushort h) {
  union { uint32_t u; float f; } x; x.u = (uint32_t)h << 16;
  return x.f;
}

// ---------------- small prep kernels ----------------

__global__ void k_cast(const float* __restrict__ s, ushort* __restrict__ d, int n) {
  int i = blockIdx.x * 256 + threadIdx.x;
  if (i < n) d[i] = f2bf(s[i]);
}

// Wm with columns permuted to head-major: dst[co][h*64+d] = Wm[co][d*4+h]
__global__ void k_cast_wm_perm(const float* __restrict__ s, ushort* __restrict__ d) {
  int i = blockIdx.x * 256 + threadIdx.x;   // 65536
  int co = i >> 8, j = i & 255;
  int h = j >> 6, dd = j & 63;
  d[i] = f2bf(s[co * NC + dd * NH + h]);
}

// X [b][C][N] f32 -> XT [b][N][C] bf16
__global__ void k_transpose_cast(const float* __restrict__ s, ushort* __restrict__ d) {
  int n = blockIdx.x * 256 + threadIdx.x;
  int c0 = blockIdx.y * 8;
  int b = blockIdx.z;
  const float* p = s + ((size_t)b * NC + c0) * NN + n;
  union { ushort u[8]; uint4 v; } t;
#pragma unroll
  for (int i = 0; i < 8; ++i) t.u[i] = f2bf(p[(size_t)i * NN]);
  *(uint4*)(d + ((size_t)b * NN + n) * NC + c0) = t.v;
}

// k_nat [b][d*4+h][n] bf16 -> kt [(b*4+h)][n][d] bf16
__global__ void k_head_transpose(const ushort* __restrict__ s, ushort* __restrict__ d) {
  int n = blockIdx.x * 256 + threadIdx.x;
  int d0 = blockIdx.y * 8;
  int z = blockIdx.z, b = z >> 2, h = z & 3;
  const ushort* p = s + ((size_t)b * NC + (size_t)d0 * NH + h) * NN + n;
  union { ushort u[8]; uint4 v; } t;
#pragma unroll
  for (int i = 0; i < 8; ++i) t.u[i] = p[(size_t)i * NH * NN];
  *(uint4*)(d + ((size_t)z * NN + n) * ND + d0) = t.v;
}

__global__ void k_bn_finalize(const float* __restrict__ stats, const float* __restrict__ gamma,
                              const float* __restrict__ beta, float4* __restrict__ aff) {
  int c = blockIdx.x * 256 + threadIdx.x;
  if (c >= NC2) return;
  const float inv_n = 1.f / (float)(NB * NN);
  float mu  = stats[c * 2] * inv_n;
  float var = stats[c * 2 + 1] * inv_n - mu * mu;
  float isg = gamma[c] * rsqrtf(var + 1e-5f);
  aff[c] = make_float4(mu, isg, beta[c], 0.f);
}

// ---------------- fused flash attention (recompute, barrier-free) ----------------
// 1024 blocks = 8 XCD x 4 bh x 32 q-strips of 64 rows. 256 thr = 4 waves;
// wave w owns q-rows [w*16, w*16+16). K/V fragments read straight from
// global (L2-resident per (b,h)); only P round-trips an 8 KB swizzled LDS.
// attn stores: vectorized float4 from the LDS bf16 P tile, issued LAST in
// each tile-iteration (never ahead of a load in the vmcnt FIFO), nontemporal.

__global__ __launch_bounds__(256, 4) void k_attn(
    const ushort* __restrict__ q_nat, const ushort* __restrict__ kt,
    const ushort* __restrict__ vnat, float* __restrict__ attn,
    ushort* __restrict__ xT) {
  __shared__ ushort Pl[64 * 64];   // [row][col] bf16, byte ^= (row&7)<<4

  const int tid = threadIdx.x;
  const int lane = tid & 63, w = tid >> 6;
  const int lr = lane & 15, lg = lane >> 4;

  int flat = blockIdx.x;
  int xcd = flat & 7, idx = flat >> 3;
  int z = xcd * 4 + (idx >> 5);       // bh index: 4 per XCD -> K/V L2-resident
  int r0 = (idx & 31) * 64;
  int b = z >> 2, h = z & 3;

  // preload Q A-fragments (rows w*16+lr) from q_nat [b][d*4+h][n]
  bf16x8 aq[2];
  {
    int qrow = r0 + w * 16 + lr;
#pragma unroll
    for (int ks = 0; ks < 2; ++ks) {
      union { ushort u[8]; bf16x8 v; } t;
#pragma unroll
      for (int e = 0; e < 8; ++e) {
        int d = ks * 32 + lg * 8 + e;
        t.u[e] = q_nat[((size_t)b * NC + d * 4 + h) * NN + qrow];
      }
      aq[ks] = t.v;
    }
  }

  const ushort* kbase = kt + (size_t)z * NN * ND;
  const ushort* vbase = vnat + ((size_t)b * NC + h) * NN;

  float m_run[4], s_run[4];
#pragma unroll
  for (int j = 0; j < 4; ++j) { m_run[j] = -INFINITY; s_run[j] = 0.f; }

  // ---- pass 1: online row max / sum (registers only, no barriers) ----
  // K fragments double-buffered across iterations (cross-iter prefetch).
  bf16x8 kc[2][4], kn[2][4];
#pragma unroll
  for (int ks = 0; ks < 2; ++ks)
#pragma unroll
    for (int fc = 0; fc < 4; ++fc)
      kc[ks][fc] = *(const bf16x8*)(kbase + ((size_t)fc * 16 + lr) * ND + ks * 32 + lg * 8);

  for (int t = 0; t < 32; ++t) {
    int tn = t < 31 ? t + 1 : 31;
#pragma unroll
    for (int ks = 0; ks < 2; ++ks)
#pragma unroll
      for (int fc = 0; fc < 4; ++fc)
        kn[ks][fc] = *(const bf16x8*)(kbase + ((size_t)tn * 64 + fc * 16 + lr) * ND + ks * 32 + lg * 8);
    f32x4 sa[4] = {};
#pragma unroll
    for (int ks = 0; ks < 2; ++ks)
#pragma unroll
      for (int fc = 0; fc < 4; ++fc)
        sa[fc] = __builtin_amdgcn_mfma_f32_16x16x32_bf16(aq[ks], kc[ks][fc], sa[fc], 0, 0, 0);
#pragma unroll
    for (int fc = 0; fc < 4; ++fc)
#pragma unroll
      for (int j = 0; j < 4; ++j) sa[fc][j] *= 0.125f;
    float tm[4], es[4];
#pragma unroll
    for (int j = 0; j < 4; ++j)
      tm[j] = fmaxf(fmaxf(sa[0][j], sa[1][j]), fmaxf(sa[2][j], sa[3][j]));
#pragma unroll
    for (int o = 1; o < 16; o <<= 1)
#pragma unroll
      for (int j = 0; j < 4; ++j) tm[j] = fmaxf(tm[j], __shfl_xor(tm[j], o));
#pragma unroll
    for (int j = 0; j < 4; ++j) {
      float mn = fmaxf(m_run[j], tm[j]);
      es[j] = __expf(sa[0][j] - mn) + __expf(sa[1][j] - mn)
            + __expf(sa[2][j] - mn) + __expf(sa[3][j] - mn);
      float corr = __expf(m_run[j] - mn);
      s_run[j] *= corr;
      m_run[j] = mn;
    }
#pragma unroll
    for (int o = 1; o < 16; o <<= 1)
#pragma unroll
      for (int j = 0; j < 4; ++j) es[j] += __shfl_xor(es[j], o);
#pragma unroll
    for (int j = 0; j < 4; ++j) s_run[j] += es[j];
#pragma unroll
    for (int ks = 0; ks < 2; ++ks)
#pragma unroll
      for (int fc = 0; fc < 4; ++fc) kc[ks][fc] = kn[ks][fc];
  }

  float inv_s[4];
#pragma unroll
  for (int j = 0; j < 4; ++j) inv_s[j] = 1.f / s_run[j];

  // ---- pass 2: recompute S, PV via LDS P-tile, vectorized attn store last ----
  f32x4 acc[4] = {};
  const int prow = w * 16 + lr;
  const int srow = w * 16 + (lane >> 4);   // + k*4 for the store sweep
  char* plb = (char*)Pl;
  for (int t = 0; t < 32; ++t) {
    // issue all loads for this tile first (K then V); stores only at the end
    bf16x8 bk[2][4], bv[2][4];
#pragma unroll
    for (int ks = 0; ks < 2; ++ks)
#pragma unroll
      for (int fc = 0; fc < 4; ++fc)
        bk[ks][fc] = *(const bf16x8*)(kbase + ((size_t)t * 64 + fc * 16 + lr) * ND + ks * 32 + lg * 8);
#pragma unroll
    for (int ks = 0; ks < 2; ++ks)
#pragma unroll
      for (int fc = 0; fc < 4; ++fc)
        bv[ks][fc] = *(const bf16x8*)(vbase + (size_t)(fc * 16 + lr) * 4 * NN + t * 64 + ks * 32 + lg * 8);
    f32x4 sa[4] = {};
#pragma unroll
    for (int ks = 0; ks < 2; ++ks)
#pragma unroll
      for (int fc = 0; fc < 4; ++fc)
        sa[fc] = __builtin_amdgcn_mfma_f32_16x16x32_bf16(aq[ks], bk[ks][fc], sa[fc], 0, 0, 0);
    // normalized P -> LDS (bf16, swizzled)
#pragma unroll
    for (int fc = 0; fc < 4; ++fc)
#pragma unroll
      for (int j = 0; j < 4; ++j) {
        int row = w * 16 + lg * 4 + j;
        float p = __expf(sa[fc][j] * 0.125f - m_run[j]) * inv_s[j];
        int byte = (row << 7) + ((fc * 16 + lr) << 1);
        byte ^= (row & 7) << 4;
        *(ushort*)(plb + byte) = f2bf(p);
      }
    // PV MFMA
#pragma unroll
    for (int ks = 0; ks < 2; ++ks) {
      int abyte = (prow << 7) + ks * 64 + lg * 16;
      abyte ^= (prow & 7) << 4;
      bf16x8 ap = *(const bf16x8*)(plb + abyte);
#pragma unroll
      for (int fc = 0; fc < 4; ++fc)
        acc[fc] = __builtin_amdgcn_mfma_f32_16x16x32_bf16(ap, bv[ks][fc], acc[fc], 0, 0, 0);
    }
    // attn store: 16 lanes cover 256B of one row; 4 rows per instr; NT to
    // keep the streaming 545MB out of L2 (K/V working set lives there)
    float* abase = attn + ((size_t)z * NN + r0) * NN + t * 64;
#pragma unroll
    for (int k = 0; k < 4; ++k) {
      int row = srow + k * 4;
      int byte = (row << 7) + ((lane & 15) << 3);
      byte ^= (row & 7) << 4;
      const ushort* pq = (const ushort*)(plb + byte);
      f32x4 vv = { bf2f(pq[0]), bf2f(pq[1]), bf2f(pq[2]), bf2f(pq[3]) };
      __builtin_nontemporal_store(vv, (f32x4*)(abase + (size_t)row * NN + (lane & 15) * 4));
    }
  }
  // epilogue: xT[b][n][h*64+d]
#pragma unroll
  for (int fc = 0; fc < 4; ++fc)
#pragma unroll
    for (int j = 0; j < 4; ++j) {
      int n = r0 + w * 16 + lg * 4 + j;
      xT[((size_t)b * NN + n) * NC + h * 64 + fc * 16 + lr] = f2bf(acc[fc][j]);
    }
}

// ---------------- generic MFMA GEMM: D[r][c] = sum_k A[r][k]*B[c][k] ----------------

enum GemmMode { M_PROJ = 0, M_WM, M_W1, M_W2 };

template <int MODE>
__global__ __launch_bounds__(256) void k_gemm(
    const ushort* __restrict__ A, const ushort* __restrict__ A2,
    const ushort* __restrict__ Bm,
    const float* __restrict__ bias, const float4* __restrict__ aff,
    float* __restrict__ stats, float* __restrict__ outf, ushort* __restrict__ outb) {
  constexpr int BR = 128;
  constexpr int BC = 128;
  constexpr int KT = (MODE == M_PROJ || MODE == M_WM) ? 256 : 512;
  constexpr int FR = 4;
  constexpr int FC = 4;
  constexpr int LDL = 72;

  __shared__ ushort ldsA[BR * LDL];
  __shared__ ushort ldsB[BC * LDL];

  const int tid = threadIdx.x;
  const int lane = tid & 63, wave = tid >> 6;
  const int wr = (wave >> 1) * (FR * 16), wc = (wave & 1) * (FC * 16);
  const int lr = lane & 15, lk = (lane >> 4) * 8;
  const int c0 = blockIdx.x * BC, r0 = blockIdx.y * BR;
  const size_t z = blockIdx.z;

  f32x4 acc[FR][FC] = {};

  for (int kk = 0; kk < KT; kk += 64) {
    // ---- stage A ----
    {
      const ushort* src; int ld;
      if constexpr (MODE == M_PROJ)        { src = A + (size_t)r0 * NC + kk; ld = NC; }
      else if constexpr (MODE == M_WM)     { src = A + (z * NN + r0) * (size_t)NC + kk; ld = NC; }
      else if constexpr (MODE == M_W1) {
        if (kk < NC) src = A  + (z * NN + r0) * (size_t)NC + kk;
        else         src = A2 + (z * NN + r0) * (size_t)NC + (kk - NC);
        ld = NC;
      } else { src = A + (size_t)r0 * NC2 + kk; ld = NC2; }   // M_W2
#pragma unroll
      for (int i = 0; i < BR / 32; ++i) {
        int off = (tid + i * 256) * 8, row = off >> 6, k = off & 63;
        *(uint4*)&ldsA[row * LDL + k] = *(const uint4*)(src + (size_t)row * ld + k);
      }
    }
    // ---- stage B ----
    if constexpr (MODE == M_W2) {
      const ushort* src = Bm + (z * NN + c0) * (size_t)NC2 + kk;
#pragma unroll
      for (int i = 0; i < BC / 32; ++i) {
        int off = (tid + i * 256) * 8, row = off >> 6, k = off & 63;
        union { ushort u[8]; uint4 v; } t, o;
        t.v = *(const uint4*)(src + (size_t)row * NC2 + k);
#pragma unroll
        for (int e = 0; e < 8; ++e) {
          float4 pr = aff[kk + k + e];
          float y = (bf2f(t.u[e]) - pr.x) * pr.y + pr.z;
          y = y > 0.f ? y : 0.2f * y;
          o.u[e] = f2bf(y);
        }
        *(uint4*)&ldsB[row * LDL + k] = o.v;
      }
    } else {
      const ushort* src; int ld;
      if constexpr (MODE == M_PROJ)        { src = Bm + (z * NN + c0) * (size_t)NC + kk; ld = NC; }
      else if constexpr (MODE == M_WM)     { src = Bm + (size_t)c0 * NC + kk; ld = NC; }
      else                                  { src = Bm + (size_t)c0 * NC2 + kk; ld = NC2; }  // M_W1
#pragma unroll
      for (int i = 0; i < BC / 32; ++i) {
        int off = (tid + i * 256) * 8, row = off >> 6, k = off & 63;
        *(uint4*)&ldsB[row * LDL + k] = *(const uint4*)(src + (size_t)row * ld + k);
      }
    }
    __syncthreads();
#pragma unroll
    for (int ks = 0; ks < 2; ++ks) {
      bf16x8 afr[FR], bfr[FC];
#pragma unroll
      for (int fr = 0; fr < FR; ++fr)
        afr[fr] = *(const bf16x8*)&ldsA[(wr + fr * 16 + lr) * LDL + ks * 32 + lk];
#pragma unroll
      for (int fc = 0; fc < FC; ++fc)
        bfr[fc] = *(const bf16x8*)&ldsB[(wc + fc * 16 + lr) * LDL + ks * 32 + lk];
#pragma unroll
      for (int fr = 0; fr < FR; ++fr)
#pragma unroll
        for (int fc = 0; fc < FC; ++fc)
          acc[fr][fc] = __builtin_amdgcn_mfma_f32_16x16x32_bf16(afr[fr], bfr[fc], acc[fr][fc], 0, 0, 0);
    }
    __syncthreads();
  }

  float sfc[FC], qfc[FC];
#pragma unroll
  for (int fc = 0; fc < FC; ++fc) { sfc[fc] = 0.f; qfc[fc] = 0.f; }
#pragma unroll
  for (int fr = 0; fr < FR; ++fr)
#pragma unroll
    for (int fc = 0; fc < FC; ++fc)
#pragma unroll
      for (int j = 0; j < 4; ++j) {
        int r = r0 + wr + fr * 16 + (lane >> 4) * 4 + j;
        int c = c0 + wc + fc * 16 + lr;
        float v = acc[fr][fc][j];
        if constexpr (MODE == M_PROJ) {
          v += bias[r];
          outb[(z * NC + r) * (size_t)NN + c] = f2bf(v);
        } else if constexpr (MODE == M_WM) {
          v += bias[c];
          outb[(z * NN + r) * (size_t)NC + c] = f2bf(v);
        } else if constexpr (MODE == M_W1) {
          v += bias[c];
          outb[(z * NN + r) * (size_t)NC2 + c] = f2bf(v);
          sfc[fc] += v; qfc[fc] += v * v;
        } else {  // M_W2
          v += bias[r];
          outf[(z * NC + r) * (size_t)NN + c] = v;
        }
      }
  if constexpr (MODE == M_W1) {
#pragma unroll
    for (int fc = 0; fc < FC; ++fc) {
      float s1 = sfc[fc], s2 = qfc[fc];
      s1 += __shfl_xor(s1, 16); s1 += __shfl_xor(s1, 32);
      s2 += __shfl_xor(s2, 16); s2 += __shfl_xor(s2, 32);
      if (lane < 16) {
        int ch = c0 + wc + fc * 16 + lane;
        atomicAdd(&stats[ch * 2],     s1);
        atomicAdd(&stats[ch * 2 + 1], s2);
      }
    }
  }
}

// ---------------- launch ----------------

extern "C" void kernel_launch(void* const* d_in, const int* in_sizes, int n_in,
                              void* d_out, int out_size, void* d_ws, size_t ws_size,
                              hipStream_t stream) {
  const float* iq    = (const float*)d_in[0];
  const float* keyi  = (const float*)d_in[1];
  const float* vali  = (const float*)d_in[2];
  const float* Wq = (const float*)d_in[3];  const float* bq = (const float*)d_in[4];
  const float* Wk = (const float*)d_in[5];  const float* bk = (const float*)d_in[6];
  const float* Wv = (const float*)d_in[7];  const float* bv = (const float*)d_in[8];
  const float* Wm = (const float*)d_in[9];  const float* bm = (const float*)d_in[10];
  const float* W1 = (const float*)d_in[11]; const float* b1 = (const float*)d_in[12];
  const float* gamma = (const float*)d_in[13]; const float* beta = (const float*)d_in[14];
  const float* W2 = (const float*)d_in[15]; const float* b2 = (const float*)d_in[16];

  float* out  = (float*)d_out;
  float* attn = out + (size_t)NB * NC * NN;   // [B,H,N,N] f32

  uint8_t* cur = (uint8_t*)d_ws;
  auto alloc = [&](size_t bytes) { uint8_t* p = cur; cur += (bytes + 255) & ~(size_t)255; return p; };
  ushort* wq_b = (ushort*)alloc((size_t)NC * NC * 2);
  ushort* wk_b = (ushort*)alloc((size_t)NC * NC * 2);
  ushort* wv_b = (ushort*)alloc((size_t)NC * NC * 2);
  ushort* wm_b = (ushort*)alloc((size_t)NC * NC * 2);
  ushort* w1_b = (ushort*)alloc((size_t)NC2 * NC2 * 2);
  ushort* w2_b = (ushort*)alloc((size_t)NC * NC2 * 2);
  const size_t TN = (size_t)NB * NN * NC;
  ushort* iqT   = (ushort*)alloc(TN * 2);  // init_query^T  [b][n][c]
  ushort* kT    = (ushort*)alloc(TN * 2);
  ushort* vT    = (ushort*)alloc(TN * 2);
  ushort* q_nat = (ushort*)alloc(TN * 2);  // [b][c][n]
  ushort* k_nat = (ushort*)alloc(TN * 2);
  ushort* v_nat = (ushort*)alloc(TN * 2);
  ushort* kt    = (ushort*)alloc(TN * 2);  // [(b h)][n][d]
  ushort* xT    = (ushort*)alloc(TN * 2);  // attn@V, [b][n][h*64+d]
  ushort* xmT   = (ushort*)alloc(TN * 2);  // merge out^T [b][n][co]
  ushort* hT    = (ushort*)alloc((size_t)NB * NN * NC2 * 2);
  float*  stats = (float*)alloc(NC2 * 2 * 4);
  float4* aff   = (float4*)alloc(NC2 * 16);

  hipMemsetAsync(stats, 0, NC2 * 2 * 4, stream);

  k_cast<<<dim3(256), 256, 0, stream>>>(Wq, wq_b, NC * NC);
  k_cast<<<dim3(256), 256, 0, stream>>>(Wk, wk_b, NC * NC);
  k_cast<<<dim3(256), 256, 0, stream>>>(Wv, wv_b, NC * NC);
  k_cast_wm_perm<<<dim3(256), 256, 0, stream>>>(Wm, wm_b);
  k_cast<<<dim3(1024), 256, 0, stream>>>(W1, w1_b, NC2 * NC2);
  k_cast<<<dim3(512), 256, 0, stream>>>(W2, w2_b, NC * NC2);

  k_transpose_cast<<<dim3(8, 32, 8), 256, 0, stream>>>(iq,   iqT);
  k_transpose_cast<<<dim3(8, 32, 8), 256, 0, stream>>>(keyi, kT);
  k_transpose_cast<<<dim3(8, 32, 8), 256, 0, stream>>>(vali, vT);

  k_gemm<M_PROJ><<<dim3(16, 2, 8), 256, 0, stream>>>(wq_b, nullptr, iqT, bq, nullptr, nullptr, nullptr, q_nat);
  k_gemm<M_PROJ><<<dim3(16, 2, 8), 256, 0, stream>>>(wk_b, nullptr, kT,  bk, nullptr, nullptr, nullptr, k_nat);
  k_gemm<M_PROJ><<<dim3(16, 2, 8), 256, 0, stream>>>(wv_b, nullptr, vT,  bv, nullptr, nullptr, nullptr, v_nat);

  k_head_transpose<<<dim3(8, 8, 32), 256, 0, stream>>>(k_nat, kt);

  k_attn<<<dim3(1024), 256, 0, stream>>>(q_nat, kt, v_nat, attn, xT);

  k_gemm<M_WM><<<dim3(2, 16, 8), 256, 0, stream>>>(xT, nullptr, wm_b, bm, nullptr, nullptr, nullptr, xmT);

  k_gemm<M_W1><<<dim3(4, 16, 8), 256, 0, stream>>>(xmT, iqT, w1_b, b1, nullptr, stats, nullptr, hT);

  k_bn_finalize<<<dim3(2), 256, 0, stream>>>(stats, gamma, beta, aff);

  k_gemm<M_W2><<<dim3(16, 2, 8), 256, 0, stream>>>(w2_b, nullptr, hT, b2, aff, nullptr, out, nullptr);
}

// Round 6
// 329.142 us; speedup vs baseline: 2.5379x; 1.5871x over previous
//
#include <hip/hip_runtime.h>
#include <stdint.h>

typedef __bf16 bf16x8 __attribute__((ext_vector_type(8)));
typedef float f32x4 __attribute__((ext_vector_type(4)));

constexpr int NB = 8;      // batch
constexpr int NC = 256;    // channels C
constexpr int NN = 2048;   // sequence N
constexpr int NH = 4;      // heads
constexpr int ND = 64;     // head dim
constexpr int NC2 = 512;   // 2C

__device__ __forceinline__ ushort f2bf(float f) {
  union { float f; uint32_t u; } x; x.f = f;
  return (ushort)((x.u + 0x7FFFu + ((x.u >> 16) & 1u)) >> 16);
}
__device__ __forceinline__ float bf2f(ushort h) {
  union { uint32_t u; float f; } x; x.u = (uint32_t)h << 16;
  return x.f;
}

// ---------------- small prep kernels ----------------

__global__ void k_cast(const float* __restrict__ s, ushort* __restrict__ d, int n) {
  int i = blockIdx.x * 256 + threadIdx.x;
  if (i < n) d[i] = f2bf(s[i]);
}

// Wm with columns permuted to head-major: dst[co][h*64+d] = Wm[co][d*4+h]
__global__ void k_cast_wm_perm(const float* __restrict__ s, ushort* __restrict__ d) {
  int i = blockIdx.x * 256 + threadIdx.x;   // 65536
  int co = i >> 8, j = i & 255;
  int h = j >> 6, dd = j & 63;
  d[i] = f2bf(s[co * NC + dd * NH + h]);
}

// X [b][C][N] f32 -> XT [b][N][C] bf16
__global__ void k_transpose_cast(const float* __restrict__ s, ushort* __restrict__ d) {
  int n = blockIdx.x * 256 + threadIdx.x;
  int c0 = blockIdx.y * 8;
  int b = blockIdx.z;
  const float* p = s + ((size_t)b * NC + c0) * NN + n;
  union { ushort u[8]; uint4 v; } t;
#pragma unroll
  for (int i = 0; i < 8; ++i) t.u[i] = f2bf(p[(size_t)i * NN]);
  *(uint4*)(d + ((size_t)b * NN + n) * NC + c0) = t.v;
}

// x_nat [b][d*4+h][n] bf16 -> xt [(b*4+h)][n][d] bf16
__global__ void k_head_transpose(const ushort* __restrict__ s, ushort* __restrict__ d) {
  int n = blockIdx.x * 256 + threadIdx.x;
  int d0 = blockIdx.y * 8;
  int z = blockIdx.z, b = z >> 2, h = z & 3;
  const ushort* p = s + ((size_t)b * NC + (size_t)d0 * NH + h) * NN + n;
  union { ushort u[8]; uint4 v; } t;
#pragma unroll
  for (int i = 0; i < 8; ++i) t.u[i] = p[(size_t)i * NH * NN];
  *(uint4*)(d + ((size_t)z * NN + n) * ND + d0) = t.v;
}

__global__ void k_bn_finalize(const float* __restrict__ stats, const float* __restrict__ gamma,
                              const float* __restrict__ beta, float4* __restrict__ aff) {
  int c = blockIdx.x * 256 + threadIdx.x;
  if (c >= NC2) return;
  const float inv_n = 1.f / (float)(NB * NN);
  float mu  = stats[c * 2] * inv_n;
  float var = stats[c * 2 + 1] * inv_n - mu * mu;
  float isg = gamma[c] * rsqrtf(var + 1e-5f);
  aff[c] = make_float4(mu, isg, beta[c], 0.f);
}

// ---------------- fused flash attention (LDS-staged, double-buffered) ----------------
// 1024 blocks = 8 XCD x 4 bh x 32 q-strips of 64 rows; 4 waves, wave w owns
// q-rows [w*16, w*16+16). K/V tiles (64x64 bf16, 8 KB) are reg-staged into
// XOR-swizzled LDS (issue loads early, ds_write after barrier: T14), fragments
// read from LDS. P round-trips an 8 KB swizzled tile. attn written once, NT.

__device__ __forceinline__ bf16x8 ldtile(const ushort* base, int lr, int lg, int fc, int ks) {
  int row = fc * 16 + lr;
  int u = (ks * 4 + lg) ^ (lr & 7);
  return *(const bf16x8*)((const char*)base + row * 128 + u * 16);
}

__global__ __launch_bounds__(256, 4) void k_attn(
    const ushort* __restrict__ qt, const ushort* __restrict__ kt,
    const ushort* __restrict__ vnat, float* __restrict__ attn,
    ushort* __restrict__ xT) {
  __shared__ ushort Kl[2][4096];   // 2 x 8 KB, swizzled: unit ^= row&7
  __shared__ ushort Vl[2][4096];
  __shared__ ushort Pl[4096];      // 64x64 bf16, byte ^= (row&7)<<4

  const int tid = threadIdx.x;
  const int lane = tid & 63, w = tid >> 6;
  const int lr = lane & 15, lg = lane >> 4;

  int flat = blockIdx.x;
  int xcd = flat & 7, idx = flat >> 3;
  int z = xcd * 4 + (idx >> 5);       // 4 bh per XCD -> K/V L2-resident
  int r0 = (idx & 31) * 64;
  int b = z >> 2, h = z & 3;

  const ushort* kbase = kt + (size_t)z * NN * ND;
  const ushort* vbase = vnat + ((size_t)b * NC + h) * NN;

  // staging geometry: 512 segments of 16B; thread does segs tid and 256+tid
  const int sr0 = tid >> 3, sc0 = tid & 7;
  const int sr1 = 32 + sr0;
  const int d0 = sr0 * 128 + ((sc0 ^ (sr0 & 7)) << 4);
  const int d1 = sr1 * 128 + ((sc0 ^ (sr1 & 7)) << 4);

  // Q fragments (coalesced from qt [z][n][d])
  bf16x8 aq0, aq1;
  {
    const ushort* qp = qt + ((size_t)z * NN + r0 + w * 16 + lr) * ND;
    aq0 = *(const bf16x8*)(qp + lg * 8);
    aq1 = *(const bf16x8*)(qp + 32 + lg * 8);
  }

  uint4 gk0, gk1, gv0, gv1;

  // ---- pass 1 prologue: stage K tile 0 ----
  gk0 = *(const uint4*)(kbase + (size_t)sr0 * ND + sc0 * 8);
  gk1 = *(const uint4*)(kbase + (size_t)sr1 * ND + sc0 * 8);
  *(uint4*)((char*)Kl[0] + d0) = gk0;
  *(uint4*)((char*)Kl[0] + d1) = gk1;
  __syncthreads();

  float m_run[4], s_run[4];
#pragma unroll
  for (int j = 0; j < 4; ++j) { m_run[j] = -INFINITY; s_run[j] = 0.f; }

  // ---- pass 1: online row max / sum ----
  for (int t = 0; t < 32; ++t) {
    int kb = t & 1;
    if (t < 31) {
      gk0 = *(const uint4*)(kbase + ((size_t)(t + 1) * 64 + sr0) * ND + sc0 * 8);
      gk1 = *(const uint4*)(kbase + ((size_t)(t + 1) * 64 + sr1) * ND + sc0 * 8);
    }
    f32x4 sa[4] = {};
#pragma unroll
    for (int ks = 0; ks < 2; ++ks) {
      bf16x8 aqk = ks ? aq1 : aq0;
#pragma unroll
      for (int fc = 0; fc < 4; ++fc)
        sa[fc] = __builtin_amdgcn_mfma_f32_16x16x32_bf16(aqk, ldtile(Kl[kb], lr, lg, fc, ks), sa[fc], 0, 0, 0);
    }
#pragma unroll
    for (int fc = 0; fc < 4; ++fc)
#pragma unroll
      for (int j = 0; j < 4; ++j) sa[fc][j] *= 0.125f;
    float tm[4], es[4];
#pragma unroll
    for (int j = 0; j < 4; ++j)
      tm[j] = fmaxf(fmaxf(sa[0][j], sa[1][j]), fmaxf(sa[2][j], sa[3][j]));
#pragma unroll
    for (int o = 1; o < 16; o <<= 1)
#pragma unroll
      for (int j = 0; j < 4; ++j) tm[j] = fmaxf(tm[j], __shfl_xor(tm[j], o));
#pragma unroll
    for (int j = 0; j < 4; ++j) {
      float mn = fmaxf(m_run[j], tm[j]);
      es[j] = __expf(sa[0][j] - mn) + __expf(sa[1][j] - mn)
            + __expf(sa[2][j] - mn) + __expf(sa[3][j] - mn);
      s_run[j] *= __expf(m_run[j] - mn);
      m_run[j] = mn;
    }
#pragma unroll
    for (int o = 1; o < 16; o <<= 1)
#pragma unroll
      for (int j = 0; j < 4; ++j) es[j] += __shfl_xor(es[j], o);
#pragma unroll
    for (int j = 0; j < 4; ++j) s_run[j] += es[j];
    __syncthreads();
    if (t < 31) {
      *(uint4*)((char*)Kl[kb ^ 1] + d0) = gk0;
      *(uint4*)((char*)Kl[kb ^ 1] + d1) = gk1;
    }
    __syncthreads();
  }

  float inv_s[4];
#pragma unroll
  for (int j = 0; j < 4; ++j) inv_s[j] = 1.f / s_run[j];

  // ---- pass 2 prologue: stage K,V tile 0 ----
  gk0 = *(const uint4*)(kbase + (size_t)sr0 * ND + sc0 * 8);
  gk1 = *(const uint4*)(kbase + (size_t)sr1 * ND + sc0 * 8);
  gv0 = *(const uint4*)(vbase + (size_t)sr0 * 4 * NN + sc0 * 8);
  gv1 = *(const uint4*)(vbase + (size_t)sr1 * 4 * NN + sc0 * 8);
  *(uint4*)((char*)Kl[0] + d0) = gk0;
  *(uint4*)((char*)Kl[0] + d1) = gk1;
  *(uint4*)((char*)Vl[0] + d0) = gv0;
  *(uint4*)((char*)Vl[0] + d1) = gv1;
  __syncthreads();

  // ---- pass 2: recompute S, write attn once, PV ----
  f32x4 acc[4] = {};
  const int prow = w * 16 + lr;
  char* plb = (char*)Pl;
  for (int t = 0; t < 32; ++t) {
    int kb = t & 1;
    if (t < 31) {
      gk0 = *(const uint4*)(kbase + ((size_t)(t + 1) * 64 + sr0) * ND + sc0 * 8);
      gk1 = *(const uint4*)(kbase + ((size_t)(t + 1) * 64 + sr1) * ND + sc0 * 8);
      gv0 = *(const uint4*)(vbase + (size_t)sr0 * 4 * NN + (t + 1) * 64 + sc0 * 8);
      gv1 = *(const uint4*)(vbase + (size_t)sr1 * 4 * NN + (t + 1) * 64 + sc0 * 8);
    }
    f32x4 sa[4] = {};
#pragma unroll
    for (int ks = 0; ks < 2; ++ks) {
      bf16x8 aqk = ks ? aq1 : aq0;
#pragma unroll
      for (int fc = 0; fc < 4; ++fc)
        sa[fc] = __builtin_amdgcn_mfma_f32_16x16x32_bf16(aqk, ldtile(Kl[kb], lr, lg, fc, ks), sa[fc], 0, 0, 0);
    }
    // normalized P -> LDS (bf16, swizzled)
#pragma unroll
    for (int fc = 0; fc < 4; ++fc)
#pragma unroll
      for (int j = 0; j < 4; ++j) {
        int row = w * 16 + lg * 4 + j;
        float p = __expf(sa[fc][j] * 0.125f - m_run[j]) * inv_s[j];
        int byte = (row << 7) + ((fc * 16 + lr) << 1);
        byte ^= (row & 7) << 4;
        *(ushort*)(plb + byte) = f2bf(p);
      }
    // attn store early (gives stores a PV-phase to retire before the barrier)
    float* abase = attn + ((size_t)z * NN + r0) * NN + t * 64;
#pragma unroll
    for (int k = 0; k < 4; ++k) {
      int row = w * 16 + lg + k * 4;
      int byte = (row << 7) + (lr << 3);
      byte ^= (row & 7) << 4;
      const ushort* pq = (const ushort*)(plb + byte);
      f32x4 vv = { bf2f(pq[0]), bf2f(pq[1]), bf2f(pq[2]), bf2f(pq[3]) };
      __builtin_nontemporal_store(vv, (f32x4*)(abase + (size_t)row * NN + lr * 4));
    }
    // PV MFMA from LDS P and V
#pragma unroll
    for (int ks = 0; ks < 2; ++ks) {
      int abyte = (prow << 7) + ks * 64 + lg * 16;
      abyte ^= (lr & 7) << 4;
      bf16x8 ap = *(const bf16x8*)(plb + abyte);
#pragma unroll
      for (int fc = 0; fc < 4; ++fc)
        acc[fc] = __builtin_amdgcn_mfma_f32_16x16x32_bf16(ap, ldtile(Vl[kb], lr, lg, fc, ks), acc[fc], 0, 0, 0);
    }
    __syncthreads();
    if (t < 31) {
      *(uint4*)((char*)Kl[kb ^ 1] + d0) = gk0;
      *(uint4*)((char*)Kl[kb ^ 1] + d1) = gk1;
      *(uint4*)((char*)Vl[kb ^ 1] + d0) = gv0;
      *(uint4*)((char*)Vl[kb ^ 1] + d1) = gv1;
    }
    __syncthreads();
  }
  // epilogue: xT[b][n][h*64+d]
#pragma unroll
  for (int fc = 0; fc < 4; ++fc)
#pragma unroll
    for (int j = 0; j < 4; ++j) {
      int n = r0 + w * 16 + lg * 4 + j;
      xT[((size_t)b * NN + n) * NC + h * 64 + fc * 16 + lr] = f2bf(acc[fc][j]);
    }
}

// ---------------- generic MFMA GEMM: D[r][c] = sum_k A[r][k]*B[c][k] ----------------

enum GemmMode { M_PROJ = 0, M_WM, M_W1, M_W2 };

template <int MODE>
__global__ __launch_bounds__(256) void k_gemm(
    const ushort* __restrict__ A, const ushort* __restrict__ A2,
    const ushort* __restrict__ Bm,
    const float* __restrict__ bias, const float4* __restrict__ aff,
    float* __restrict__ stats, float* __restrict__ outf, ushort* __restrict__ outb) {
  constexpr int BR = 128;
  constexpr int BC = 128;
  constexpr int KT = (MODE == M_PROJ || MODE == M_WM) ? 256 : 512;
  constexpr int FR = 4;
  constexpr int FC = 4;
  constexpr int LDL = 72;

  __shared__ ushort ldsA[BR * LDL];
  __shared__ ushort ldsB[BC * LDL];

  const int tid = threadIdx.x;
  const int lane = tid & 63, wave = tid >> 6;
  const int wr = (wave >> 1) * (FR * 16), wc = (wave & 1) * (FC * 16);
  const int lr = lane & 15, lk = (lane >> 4) * 8;
  const int c0 = blockIdx.x * BC, r0 = blockIdx.y * BR;
  const size_t z = blockIdx.z;

  f32x4 acc[FR][FC] = {};

  for (int kk = 0; kk < KT; kk += 64) {
    // ---- stage A ----
    {
      const ushort* src; int ld;
      if constexpr (MODE == M_PROJ)        { src = A + (size_t)r0 * NC + kk; ld = NC; }
      else if constexpr (MODE == M_WM)     { src = A + (z * NN + r0) * (size_t)NC + kk; ld = NC; }
      else if constexpr (MODE == M_W1) {
        if (kk < NC) src = A  + (z * NN + r0) * (size_t)NC + kk;
        else         src = A2 + (z * NN + r0) * (size_t)NC + (kk - NC);
        ld = NC;
      } else { src = A + (size_t)r0 * NC2 + kk; ld = NC2; }   // M_W2
#pragma unroll
      for (int i = 0; i < BR / 32; ++i) {
        int off = (tid + i * 256) * 8, row = off >> 6, k = off & 63;
        *(uint4*)&ldsA[row * LDL + k] = *(const uint4*)(src + (size_t)row * ld + k);
      }
    }
    // ---- stage B ----
    if constexpr (MODE == M_W2) {
      const ushort* src = Bm + (z * NN + c0) * (size_t)NC2 + kk;
#pragma unroll
      for (int i = 0; i < BC / 32; ++i) {
        int off = (tid + i * 256) * 8, row = off >> 6, k = off & 63;
        union { ushort u[8]; uint4 v; } t, o;
        t.v = *(const uint4*)(src + (size_t)row * NC2 + k);
#pragma unroll
        for (int e = 0; e < 8; ++e) {
          float4 pr = aff[kk + k + e];
          float y = (bf2f(t.u[e]) - pr.x) * pr.y + pr.z;
          y = y > 0.f ? y : 0.2f * y;
          o.u[e] = f2bf(y);
        }
        *(uint4*)&ldsB[row * LDL + k] = o.v;
      }
    } else {
      const ushort* src; int ld;
      if constexpr (MODE == M_PROJ)        { src = Bm + (z * NN + c0) * (size_t)NC + kk; ld = NC; }
      else if constexpr (MODE == M_WM)     { src = Bm + (size_t)c0 * NC + kk; ld = NC; }
      else                                  { src = Bm + (size_t)c0 * NC2 + kk; ld = NC2; }  // M_W1
#pragma unroll
      for (int i = 0; i < BC / 32; ++i) {
        int off = (tid + i * 256) * 8, row = off >> 6, k = off & 63;
        *(uint4*)&ldsB[row * LDL + k] = *(const uint4*)(src + (size_t)row * ld + k);
      }
    }
    __syncthreads();
#pragma unroll
    for (int ks = 0; ks < 2; ++ks) {
      bf16x8 afr[FR], bfr[FC];
#pragma unroll
      for (int fr = 0; fr < FR; ++fr)
        afr[fr] = *(const bf16x8*)&ldsA[(wr + fr * 16 + lr) * LDL + ks * 32 + lk];
#pragma unroll
      for (int fc = 0; fc < FC; ++fc)
        bfr[fc] = *(const bf16x8*)&ldsB[(wc + fc * 16 + lr) * LDL + ks * 32 + lk];
#pragma unroll
      for (int fr = 0; fr < FR; ++fr)
#pragma unroll
        for (int fc = 0; fc < FC; ++fc)
          acc[fr][fc] = __builtin_amdgcn_mfma_f32_16x16x32_bf16(afr[fr], bfr[fc], acc[fr][fc], 0, 0, 0);
    }
    __syncthreads();
  }

  float sfc[FC], qfc[FC];
#pragma unroll
  for (int fc = 0; fc < FC; ++fc) { sfc[fc] = 0.f; qfc[fc] = 0.f; }
#pragma unroll
  for (int fr = 0; fr < FR; ++fr)
#pragma unroll
    for (int fc = 0; fc < FC; ++fc)
#pragma unroll
      for (int j = 0; j < 4; ++j) {
        int r = r0 + wr + fr * 16 + (lane >> 4) * 4 + j;
        int c = c0 + wc + fc * 16 + lr;
        float v = acc[fr][fc][j];
        if constexpr (MODE == M_PROJ) {
          v += bias[r];
          outb[(z * NC + r) * (size_t)NN + c] = f2bf(v);
        } else if constexpr (MODE == M_WM) {
          v += bias[c];
          outb[(z * NN + r) * (size_t)NC + c] = f2bf(v);
        } else if constexpr (MODE == M_W1) {
          v += bias[c];
          outb[(z * NN + r) * (size_t)NC2 + c] = f2bf(v);
          sfc[fc] += v; qfc[fc] += v * v;
        } else {  // M_W2
          v += bias[r];
          outf[(z * NC + r) * (size_t)NN + c] = v;
        }
      }
  if constexpr (MODE == M_W1) {
#pragma unroll
    for (int fc = 0; fc < FC; ++fc) {
      float s1 = sfc[fc], s2 = qfc[fc];
      s1 += __shfl_xor(s1, 16); s1 += __shfl_xor(s1, 32);
      s2 += __shfl_xor(s2, 16); s2 += __shfl_xor(s2, 32);
      if (lane < 16) {
        int ch = c0 + wc + fc * 16 + lane;
        atomicAdd(&stats[ch * 2],     s1);
        atomicAdd(&stats[ch * 2 + 1], s2);
      }
    }
  }
}

// ---------------- launch ----------------

extern "C" void kernel_launch(void* const* d_in, const int* in_sizes, int n_in,
                              void* d_out, int out_size, void* d_ws, size_t ws_size,
                              hipStream_t stream) {
  const float* iq    = (const float*)d_in[0];
  const float* keyi  = (const float*)d_in[1];
  const float* vali  = (const float*)d_in[2];
  const float* Wq = (const float*)d_in[3];  const float* bq = (const float*)d_in[4];
  const float* Wk = (const float*)d_in[5];  const float* bk = (const float*)d_in[6];
  const float* Wv = (const float*)d_in[7];  const float* bv = (const float*)d_in[8];
  const float* Wm = (const float*)d_in[9];  const float* bm = (const float*)d_in[10];
  const float* W1 = (const float*)d_in[11]; const float* b1 = (const float*)d_in[12];
  const float* gamma = (const float*)d_in[13]; const float* beta = (const float*)d_in[14];
  const float* W2 = (const float*)d_in[15]; const float* b2 = (const float*)d_in[16];

  float* out  = (float*)d_out;
  float* attn = out + (size_t)NB * NC * NN;   // [B,H,N,N] f32

  uint8_t* cur = (uint8_t*)d_ws;
  auto alloc = [&](size_t bytes) { uint8_t* p = cur; cur += (bytes + 255) & ~(size_t)255; return p; };
  ushort* wq_b = (ushort*)alloc((size_t)NC * NC * 2);
  ushort* wk_b = (ushort*)alloc((size_t)NC * NC * 2);
  ushort* wv_b = (ushort*)alloc((size_t)NC * NC * 2);
  ushort* wm_b = (ushort*)alloc((size_t)NC * NC * 2);
  ushort* w1_b = (ushort*)alloc((size_t)NC2 * NC2 * 2);
  ushort* w2_b = (ushort*)alloc((size_t)NC * NC2 * 2);
  const size_t TN = (size_t)NB * NN * NC;
  ushort* iqT   = (ushort*)alloc(TN * 2);  // init_query^T  [b][n][c]
  ushort* kT    = (ushort*)alloc(TN * 2);
  ushort* vT    = (ushort*)alloc(TN * 2);
  ushort* q_nat = (ushort*)alloc(TN * 2);  // [b][c][n]
  ushort* k_nat = (ushort*)alloc(TN * 2);
  ushort* v_nat = (ushort*)alloc(TN * 2);
  ushort* qt    = (ushort*)alloc(TN * 2);  // [(b h)][n][d]
  ushort* kt    = (ushort*)alloc(TN * 2);  // [(b h)][n][d]
  ushort* xT    = (ushort*)alloc(TN * 2);  // attn@V, [b][n][h*64+d]
  ushort* xmT   = (ushort*)alloc(TN * 2);  // merge out^T [b][n][co]
  ushort* hT    = (ushort*)alloc((size_t)NB * NN * NC2 * 2);
  float*  stats = (float*)alloc(NC2 * 2 * 4);
  float4* aff   = (float4*)alloc(NC2 * 16);

  hipMemsetAsync(stats, 0, NC2 * 2 * 4, stream);

  k_cast<<<dim3(256), 256, 0, stream>>>(Wq, wq_b, NC * NC);
  k_cast<<<dim3(256), 256, 0, stream>>>(Wk, wk_b, NC * NC);
  k_cast<<<dim3(256), 256, 0, stream>>>(Wv, wv_b, NC * NC);
  k_cast_wm_perm<<<dim3(256), 256, 0, stream>>>(Wm, wm_b);
  k_cast<<<dim3(1024), 256, 0, stream>>>(W1, w1_b, NC2 * NC2);
  k_cast<<<dim3(512), 256, 0, stream>>>(W2, w2_b, NC * NC2);

  k_transpose_cast<<<dim3(8, 32, 8), 256, 0, stream>>>(iq,   iqT);
  k_transpose_cast<<<dim3(8, 32, 8), 256, 0, stream>>>(keyi, kT);
  k_transpose_cast<<<dim3(8, 32, 8), 256, 0, stream>>>(vali, vT);

  k_gemm<M_PROJ><<<dim3(16, 2, 8), 256, 0, stream>>>(wq_b, nullptr, iqT, bq, nullptr, nullptr, nullptr, q_nat);
  k_gemm<M_PROJ><<<dim3(16, 2, 8), 256, 0, stream>>>(wk_b, nullptr, kT,  bk, nullptr, nullptr, nullptr, k_nat);
  k_gemm<M_PROJ><<<dim3(16, 2, 8), 256, 0, stream>>>(wv_b, nullptr, vT,  bv, nullptr, nullptr, nullptr, v_nat);

  k_head_transpose<<<dim3(8, 8, 32), 256, 0, stream>>>(q_nat, qt);
  k_head_transpose<<<dim3(8, 8, 32), 256, 0, stream>>>(k_nat, kt);

  k_attn<<<dim3(1024), 256, 0, stream>>>(qt, kt, v_nat, attn, xT);

  k_gemm<M_WM><<<dim3(2, 16, 8), 256, 0, stream>>>(xT, nullptr, wm_b, bm, nullptr, nullptr, nullptr, xmT);

  k_gemm<M_W1><<<dim3(4, 16, 8), 256, 0, stream>>>(xmT, iqT, w1_b, b1, nullptr, stats, nullptr, hT);

  k_bn_finalize<<<dim3(2), 256, 0, stream>>>(stats, gamma, beta, aff);

  k_gemm<M_W2><<<dim3(16, 2, 8), 256, 0, stream>>>(w2_b, nullptr, hT, b2, aff, nullptr, out, nullptr);
}

// Round 7
// 290.650 us; speedup vs baseline: 2.8740x; 1.1324x over previous
//
#include <hip/hip_runtime.h>
#include <stdint.h>

typedef __bf16 bf16x8 __attribute__((ext_vector_type(8)));
typedef float f32x4 __attribute__((ext_vector_type(4)));

constexpr int NB = 8;      // batch
constexpr int NC = 256;    // channels C
constexpr int NN = 2048;   // sequence N
constexpr int NH = 4;      // heads
constexpr int ND = 64;     // head dim
constexpr int NC2 = 512;   // 2C
constexpr size_t TND = (size_t)NB * NN * NC;
// exp(x*0.125) == exp2(x * C2)
__device__ constexpr float C2 = 0.125f * 1.4426950408889634f;

__device__ __forceinline__ ushort f2bf(float f) {
  union { float f; uint32_t u; } x; x.f = f;
  return (ushort)((x.u + 0x7FFFu + ((x.u >> 16) & 1u)) >> 16);
}
__device__ __forceinline__ float bf2f(ushort h) {
  union { uint32_t u; float f; } x; x.u = (uint32_t)h << 16;
  return x.f;
}

// ---------------- small prep kernels ----------------

__global__ void k_cast(const float* __restrict__ s, ushort* __restrict__ d, int n) {
  int i = blockIdx.x * 256 + threadIdx.x;
  if (i < n) d[i] = f2bf(s[i]);
}

// three same-size weight casts in one launch (z picks source)
__global__ void k_cast3(const float* __restrict__ s0, const float* __restrict__ s1,
                        const float* __restrict__ s2, ushort* __restrict__ d) {
  int op = blockIdx.y;
  const float* s = op == 0 ? s0 : op == 1 ? s1 : s2;
  int i = blockIdx.x * 256 + threadIdx.x;
  d[(size_t)op * NC * NC + i] = f2bf(s[i]);
}

// Wm with columns permuted to head-major: dst[co][h*64+d] = Wm[co][d*4+h]
__global__ void k_cast_wm_perm(const float* __restrict__ s, ushort* __restrict__ d) {
  int i = blockIdx.x * 256 + threadIdx.x;   // 65536
  int co = i >> 8, j = i & 255;
  int h = j >> 6, dd = j & 63;
  d[i] = f2bf(s[co * NC + dd * NH + h]);
}

// X [b][C][N] f32 -> XT [b][N][C] bf16 ; 3 sources in one launch (z = op*8+b)
__global__ void k_tc3(const float* __restrict__ s0, const float* __restrict__ s1,
                      const float* __restrict__ s2, ushort* __restrict__ d) {
  int n = blockIdx.x * 256 + threadIdx.x;
  int c0 = blockIdx.y * 8;
  int op = blockIdx.z >> 3, b = blockIdx.z & 7;
  const float* s = op == 0 ? s0 : op == 1 ? s1 : s2;
  const float* p = s + ((size_t)b * NC + c0) * NN + n;
  union { ushort u[8]; uint4 v; } t;
#pragma unroll
  for (int i = 0; i < 8; ++i) t.u[i] = f2bf(p[(size_t)i * NN]);
  *(uint4*)(d + (size_t)op * TND + ((size_t)b * NN + n) * NC + c0) = t.v;
}

// x_nat [b][d*4+h][n] bf16 -> xt [(b*4+h)][n][d] bf16 ; q and k in one launch
__global__ void k_ht2(const ushort* __restrict__ s, ushort* __restrict__ d) {
  int n = blockIdx.x * 256 + threadIdx.x;
  int d0 = blockIdx.y * 8;
  int op = blockIdx.z >> 5, zz = blockIdx.z & 31, b = zz >> 2, h = zz & 3;
  const ushort* p = s + (size_t)op * TND + ((size_t)b * NC + (size_t)d0 * NH + h) * NN + n;
  union { ushort u[8]; uint4 v; } t;
#pragma unroll
  for (int i = 0; i < 8; ++i) t.u[i] = p[(size_t)i * NH * NN];
  *(uint4*)(d + (size_t)op * TND + ((size_t)zz * NN + n) * ND + d0) = t.v;
}

__global__ void k_bn_finalize(const float* __restrict__ stats, const float* __restrict__ gamma,
                              const float* __restrict__ beta, float4* __restrict__ aff) {
  int c = blockIdx.x * 256 + threadIdx.x;
  if (c >= NC2) return;
  const float inv_n = 1.f / (float)(NB * NN);
  float mu  = stats[c * 2] * inv_n;
  float var = stats[c * 2 + 1] * inv_n - mu * mu;
  float isg = gamma[c] * rsqrtf(var + 1e-5f);
  aff[c] = make_float4(mu, isg, beta[c], 0.f);
}

// ---------------- fused flash attention (LDS-staged, lane-private softmax) ----------------
// 1024 blocks = 8 XCD x 4 bh x 32 q-strips of 64 rows; 4 waves, wave w owns
// q-rows [w*16, w*16+16). K/V tiles reg-staged into XOR-swizzled LDS. Pass 1
// keeps per-lane (m,s) partials in RAW score units -> zero cross-lane ops in
// the hot loop; one 16-lane merge at the end. Pass 2 recomputes S, writes
// normalized attn once (vectorized NT f32x4 via the P LDS tile), PV from LDS.

__device__ __forceinline__ bf16x8 ldtile(const ushort* base, int lr, int lg, int fc, int ks) {
  int row = fc * 16 + lr;
  int u = (ks * 4 + lg) ^ (lr & 7);
  return *(const bf16x8*)((const char*)base + row * 128 + u * 16);
}

__global__ __launch_bounds__(256, 4) void k_attn(
    const ushort* __restrict__ qt, const ushort* __restrict__ kt,
    const ushort* __restrict__ vnat, float* __restrict__ attn,
    ushort* __restrict__ xT) {
  __shared__ ushort Kl[2][4096];   // 2 x 8 KB, swizzled: unit ^= row&7
  __shared__ ushort Vl[2][4096];
  __shared__ ushort Pl[4096];      // 64x64 bf16, byte ^= (row&7)<<4

  const int tid = threadIdx.x;
  const int lane = tid & 63, w = tid >> 6;
  const int lr = lane & 15, lg = lane >> 4;

  int flat = blockIdx.x;
  int xcd = flat & 7, idx = flat >> 3;
  int z = xcd * 4 + (idx >> 5);       // 4 bh per XCD -> K/V L2-resident
  int r0 = (idx & 31) * 64;
  int b = z >> 2, h = z & 3;

  const ushort* kbase = kt + (size_t)z * NN * ND;
  const ushort* vbase = vnat + ((size_t)b * NC + h) * NN;

  // staging geometry: 512 segments of 16B; thread does segs tid and 256+tid
  const int sr0 = tid >> 3, sc0 = tid & 7;
  const int sr1 = 32 + sr0;
  const int d0 = sr0 * 128 + ((sc0 ^ (sr0 & 7)) << 4);
  const int d1 = sr1 * 128 + ((sc0 ^ (sr1 & 7)) << 4);

  // Q fragments (coalesced from qt [z][n][d])
  bf16x8 aq0, aq1;
  {
    const ushort* qp = qt + ((size_t)z * NN + r0 + w * 16 + lr) * ND;
    aq0 = *(const bf16x8*)(qp + lg * 8);
    aq1 = *(const bf16x8*)(qp + 32 + lg * 8);
  }

  uint4 gk0, gk1, gv0, gv1;

  // ---- pass 1 prologue: stage K tile 0 ----
  gk0 = *(const uint4*)(kbase + (size_t)sr0 * ND + sc0 * 8);
  gk1 = *(const uint4*)(kbase + (size_t)sr1 * ND + sc0 * 8);
  *(uint4*)((char*)Kl[0] + d0) = gk0;
  *(uint4*)((char*)Kl[0] + d1) = gk1;
  __syncthreads();

  // lane-private partial softmax state (raw units)
  float m_ln[4], s_ln[4];
#pragma unroll
  for (int j = 0; j < 4; ++j) { m_ln[j] = -INFINITY; s_ln[j] = 0.f; }

  // ---- pass 1: online row max / sum, no cross-lane ----
  for (int t = 0; t < 32; ++t) {
    int kb = t & 1;
    if (t < 31) {
      gk0 = *(const uint4*)(kbase + ((size_t)(t + 1) * 64 + sr0) * ND + sc0 * 8);
      gk1 = *(const uint4*)(kbase + ((size_t)(t + 1) * 64 + sr1) * ND + sc0 * 8);
    }
    f32x4 sa[4] = {};
#pragma unroll
    for (int ks = 0; ks < 2; ++ks) {
      bf16x8 aqk = ks ? aq1 : aq0;
#pragma unroll
      for (int fc = 0; fc < 4; ++fc)
        sa[fc] = __builtin_amdgcn_mfma_f32_16x16x32_bf16(aqk, ldtile(Kl[kb], lr, lg, fc, ks), sa[fc], 0, 0, 0);
    }
#pragma unroll
    for (int j = 0; j < 4; ++j) {
      float tm = fmaxf(fmaxf(sa[0][j], sa[1][j]), fmaxf(sa[2][j], sa[3][j]));
      float mn = fmaxf(m_ln[j], tm);
      float es = exp2f((sa[0][j] - mn) * C2) + exp2f((sa[1][j] - mn) * C2)
               + exp2f((sa[2][j] - mn) * C2) + exp2f((sa[3][j] - mn) * C2);
      s_ln[j] = s_ln[j] * exp2f((m_ln[j] - mn) * C2) + es;
      m_ln[j] = mn;
    }
    __syncthreads();
    if (t < 31) {
      *(uint4*)((char*)Kl[kb ^ 1] + d0) = gk0;
      *(uint4*)((char*)Kl[kb ^ 1] + d1) = gk1;
    }
    __syncthreads();
  }

  // merge the 16 lane-partials per row (lanes sharing lg)
  float m_run[4], inv_s[4];
#pragma unroll
  for (int j = 0; j < 4; ++j) {
    float m = m_ln[j];
#pragma unroll
    for (int o = 1; o < 16; o <<= 1) m = fmaxf(m, __shfl_xor(m, o));
    float c = s_ln[j] * exp2f((m_ln[j] - m) * C2);
#pragma unroll
    for (int o = 1; o < 16; o <<= 1) c += __shfl_xor(c, o);
    m_run[j] = m;
    inv_s[j] = 1.f / c;
  }

  // ---- pass 2 prologue: stage K,V tile 0 ----
  gk0 = *(const uint4*)(kbase + (size_t)sr0 * ND + sc0 * 8);
  gk1 = *(const uint4*)(kbase + (size_t)sr1 * ND + sc0 * 8);
  gv0 = *(const uint4*)(vbase + (size_t)sr0 * 4 * NN + sc0 * 8);
  gv1 = *(const uint4*)(vbase + (size_t)sr1 * 4 * NN + sc0 * 8);
  *(uint4*)((char*)Kl[0] + d0) = gk0;
  *(uint4*)((char*)Kl[0] + d1) = gk1;
  *(uint4*)((char*)Vl[0] + d0) = gv0;
  *(uint4*)((char*)Vl[0] + d1) = gv1;
  __syncthreads();

  // ---- pass 2: recompute S, write attn once, PV ----
  f32x4 acc[4] = {};
  const int prow = w * 16 + lr;
  char* plb = (char*)Pl;
  for (int t = 0; t < 32; ++t) {
    int kb = t & 1;
    if (t < 31) {
      gk0 = *(const uint4*)(kbase + ((size_t)(t + 1) * 64 + sr0) * ND + sc0 * 8);
      gk1 = *(const uint4*)(kbase + ((size_t)(t + 1) * 64 + sr1) * ND + sc0 * 8);
      gv0 = *(const uint4*)(vbase + (size_t)sr0 * 4 * NN + (t + 1) * 64 + sc0 * 8);
      gv1 = *(const uint4*)(vbase + (size_t)sr1 * 4 * NN + (t + 1) * 64 + sc0 * 8);
    }
    f32x4 sa[4] = {};
#pragma unroll
    for (int ks = 0; ks < 2; ++ks) {
      bf16x8 aqk = ks ? aq1 : aq0;
#pragma unroll
      for (int fc = 0; fc < 4; ++fc)
        sa[fc] = __builtin_amdgcn_mfma_f32_16x16x32_bf16(aqk, ldtile(Kl[kb], lr, lg, fc, ks), sa[fc], 0, 0, 0);
    }
    // normalized P -> LDS (bf16, swizzled)
#pragma unroll
    for (int fc = 0; fc < 4; ++fc)
#pragma unroll
      for (int j = 0; j < 4; ++j) {
        int row = w * 16 + lg * 4 + j;
        float p = exp2f((sa[fc][j] - m_run[j]) * C2) * inv_s[j];
        int byte = (row << 7) + ((fc * 16 + lr) << 1);
        byte ^= (row & 7) << 4;
        *(ushort*)(plb + byte) = f2bf(p);
      }
    // attn store (vectorized NT f32x4; stores retire under the PV phase)
    float* abase = attn + ((size_t)z * NN + r0) * NN + t * 64;
#pragma unroll
    for (int k = 0; k < 4; ++k) {
      int row = w * 16 + lg + k * 4;
      int byte = (row << 7) + (lr << 3);
      byte ^= (row & 7) << 4;
      const ushort* pq = (const ushort*)(plb + byte);
      f32x4 vv = { bf2f(pq[0]), bf2f(pq[1]), bf2f(pq[2]), bf2f(pq[3]) };
      __builtin_nontemporal_store(vv, (f32x4*)(abase + (size_t)row * NN + lr * 4));
    }
    // PV MFMA from LDS P and V
#pragma unroll
    for (int ks = 0; ks < 2; ++ks) {
      int abyte = (prow << 7) + ks * 64 + lg * 16;
      abyte ^= (lr & 7) << 4;
      bf16x8 ap = *(const bf16x8*)(plb + abyte);
#pragma unroll
      for (int fc = 0; fc < 4; ++fc)
        acc[fc] = __builtin_amdgcn_mfma_f32_16x16x32_bf16(ap, ldtile(Vl[kb], lr, lg, fc, ks), acc[fc], 0, 0, 0);
    }
    __syncthreads();
    if (t < 31) {
      *(uint4*)((char*)Kl[kb ^ 1] + d0) = gk0;
      *(uint4*)((char*)Kl[kb ^ 1] + d1) = gk1;
      *(uint4*)((char*)Vl[kb ^ 1] + d0) = gv0;
      *(uint4*)((char*)Vl[kb ^ 1] + d1) = gv1;
    }
    __syncthreads();
  }
  // epilogue: xT[b][n][h*64+d]
#pragma unroll
  for (int fc = 0; fc < 4; ++fc)
#pragma unroll
    for (int j = 0; j < 4; ++j) {
      int n = r0 + w * 16 + lg * 4 + j;
      xT[((size_t)b * NN + n) * NC + h * 64 + fc * 16 + lr] = f2bf(acc[fc][j]);
    }
}

// ---------------- generic MFMA GEMM: D[r][c] = sum_k A[r][k]*B[c][k] ----------------

enum GemmMode { M_PROJ = 0, M_WM, M_W1, M_W2 };

template <int MODE>
__global__ __launch_bounds__(256) void k_gemm(
    const ushort* __restrict__ A, const ushort* __restrict__ A2,
    const ushort* __restrict__ Bm,
    const float* __restrict__ bias, const float* __restrict__ bias_k,
    const float* __restrict__ bias_v, const float4* __restrict__ aff,
    float* __restrict__ stats, float* __restrict__ outf, ushort* __restrict__ outb) {
  constexpr int BR = (MODE == M_WM || MODE == M_W2) ? 64 : 128;
  constexpr int BC = 128;
  constexpr int KT = (MODE == M_PROJ || MODE == M_WM) ? 256 : 512;
  constexpr int FR = BR / 32;
  constexpr int FC = 4;
  constexpr int LDL = 72;

  __shared__ ushort ldsA[BR * LDL];
  __shared__ ushort ldsB[BC * LDL];

  const int tid = threadIdx.x;
  const int lane = tid & 63, wave = tid >> 6;
  const int wr = (wave >> 1) * (FR * 16), wc = (wave & 1) * (FC * 16);
  const int lr = lane & 15, lk = (lane >> 4) * 8;
  const int c0 = blockIdx.x * BC, r0 = blockIdx.y * BR;
  // M_PROJ folds 3 ops (q,k,v) into z
  const int op = (MODE == M_PROJ) ? (int)(blockIdx.z >> 3) : 0;
  const size_t z = (MODE == M_PROJ) ? (blockIdx.z & 7) : blockIdx.z;

  f32x4 acc[FR][FC] = {};

  for (int kk = 0; kk < KT; kk += 64) {
    // ---- stage A ----
    {
      const ushort* src; int ld;
      if constexpr (MODE == M_PROJ)        { src = A + (size_t)op * NC * NC + (size_t)r0 * NC + kk; ld = NC; }
      else if constexpr (MODE == M_WM)     { src = A + (z * NN + r0) * (size_t)NC + kk; ld = NC; }
      else if constexpr (MODE == M_W1) {
        if (kk < NC) src = A  + (z * NN + r0) * (size_t)NC + kk;
        else         src = A2 + (z * NN + r0) * (size_t)NC + (kk - NC);
        ld = NC;
      } else { src = A + (size_t)r0 * NC2 + kk; ld = NC2; }   // M_W2
#pragma unroll
      for (int i = 0; i < BR / 32; ++i) {
        int off = (tid + i * 256) * 8, row = off >> 6, k = off & 63;
        *(uint4*)&ldsA[row * LDL + k] = *(const uint4*)(src + (size_t)row * ld + k);
      }
    }
    // ---- stage B ----
    if constexpr (MODE == M_W2) {
      const ushort* src = Bm + (z * NN + c0) * (size_t)NC2 + kk;
#pragma unroll
      for (int i = 0; i < BC / 32; ++i) {
        int off = (tid + i * 256) * 8, row = off >> 6, k = off & 63;
        union { ushort u[8]; uint4 v; } t, o;
        t.v = *(const uint4*)(src + (size_t)row * NC2 + k);
#pragma unroll
        for (int e = 0; e < 8; ++e) {
          float4 pr = aff[kk + k + e];
          float y = (bf2f(t.u[e]) - pr.x) * pr.y + pr.z;
          y = y > 0.f ? y : 0.2f * y;
          o.u[e] = f2bf(y);
        }
        *(uint4*)&ldsB[row * LDL + k] = o.v;
      }
    } else {
      const ushort* src; int ld;
      if constexpr (MODE == M_PROJ)        { src = Bm + (size_t)op * TND + (z * NN + c0) * (size_t)NC + kk; ld = NC; }
      else if constexpr (MODE == M_WM)     { src = Bm + (size_t)c0 * NC + kk; ld = NC; }
      else                                  { src = Bm + (size_t)c0 * NC2 + kk; ld = NC2; }  // M_W1
#pragma unroll
      for (int i = 0; i < BC / 32; ++i) {
        int off = (tid + i * 256) * 8, row = off >> 6, k = off & 63;
        *(uint4*)&ldsB[row * LDL + k] = *(const uint4*)(src + (size_t)row * ld + k);
      }
    }
    __syncthreads();
#pragma unroll
    for (int ks = 0; ks < 2; ++ks) {
      bf16x8 afr[FR], bfr[FC];
#pragma unroll
      for (int fr = 0; fr < FR; ++fr)
        afr[fr] = *(const bf16x8*)&ldsA[(wr + fr * 16 + lr) * LDL + ks * 32 + lk];
#pragma unroll
      for (int fc = 0; fc < FC; ++fc)
        bfr[fc] = *(const bf16x8*)&ldsB[(wc + fc * 16 + lr) * LDL + ks * 32 + lk];
#pragma unroll
      for (int fr = 0; fr < FR; ++fr)
#pragma unroll
        for (int fc = 0; fc < FC; ++fc)
          acc[fr][fc] = __builtin_amdgcn_mfma_f32_16x16x32_bf16(afr[fr], bfr[fc], acc[fr][fc], 0, 0, 0);
    }
    __syncthreads();
  }

  float sfc[FC], qfc[FC];
#pragma unroll
  for (int fc = 0; fc < FC; ++fc) { sfc[fc] = 0.f; qfc[fc] = 0.f; }
#pragma unroll
  for (int fr = 0; fr < FR; ++fr)
#pragma unroll
    for (int fc = 0; fc < FC; ++fc)
#pragma unroll
      for (int j = 0; j < 4; ++j) {
        int r = r0 + wr + fr * 16 + (lane >> 4) * 4 + j;
        int c = c0 + wc + fc * 16 + lr;
        float v = acc[fr][fc][j];
        if constexpr (MODE == M_PROJ) {
          const float* bb = op == 0 ? bias : op == 1 ? bias_k : bias_v;
          v += bb[r];
          outb[(size_t)op * TND + (z * NC + r) * (size_t)NN + c] = f2bf(v);
        } else if constexpr (MODE == M_WM) {
          v += bias[c];
          outb[(z * NN + r) * (size_t)NC + c] = f2bf(v);
        } else if constexpr (MODE == M_W1) {
          v += bias[c];
          outb[(z * NN + r) * (size_t)NC2 + c] = f2bf(v);
          sfc[fc] += v; qfc[fc] += v * v;
        } else {  // M_W2
          v += bias[r];
          outf[(z * NC + r) * (size_t)NN + c] = v;
        }
      }
  if constexpr (MODE == M_W1) {
#pragma unroll
    for (int fc = 0; fc < FC; ++fc) {
      float s1 = sfc[fc], s2 = qfc[fc];
      s1 += __shfl_xor(s1, 16); s1 += __shfl_xor(s1, 32);
      s2 += __shfl_xor(s2, 16); s2 += __shfl_xor(s2, 32);
      if (lane < 16) {
        int ch = c0 + wc + fc * 16 + lane;
        atomicAdd(&stats[ch * 2],     s1);
        atomicAdd(&stats[ch * 2 + 1], s2);
      }
    }
  }
}

// ---------------- launch ----------------

extern "C" void kernel_launch(void* const* d_in, const int* in_sizes, int n_in,
                              void* d_out, int out_size, void* d_ws, size_t ws_size,
                              hipStream_t stream) {
  const float* iq    = (const float*)d_in[0];
  const float* keyi  = (const float*)d_in[1];
  const float* vali  = (const float*)d_in[2];
  const float* Wq = (const float*)d_in[3];  const float* bq = (const float*)d_in[4];
  const float* Wk = (const float*)d_in[5];  const float* bk = (const float*)d_in[6];
  const float* Wv = (const float*)d_in[7];  const float* bv = (const float*)d_in[8];
  const float* Wm = (const float*)d_in[9];  const float* bm = (const float*)d_in[10];
  const float* W1 = (const float*)d_in[11]; const float* b1 = (const float*)d_in[12];
  const float* gamma = (const float*)d_in[13]; const float* beta = (const float*)d_in[14];
  const float* W2 = (const float*)d_in[15]; const float* b2 = (const float*)d_in[16];

  float* out  = (float*)d_out;
  float* attn = out + (size_t)NB * NC * NN;   // [B,H,N,N] f32

  uint8_t* cur = (uint8_t*)d_ws;
  auto alloc = [&](size_t bytes) { uint8_t* p = cur; cur += (bytes + 255) & ~(size_t)255; return p; };
  ushort* wq_b = (ushort*)alloc((size_t)NC * NC * 2 * 3);   // wq|wk|wv contiguous
  ushort* wm_b = (ushort*)alloc((size_t)NC * NC * 2);
  ushort* w1_b = (ushort*)alloc((size_t)NC2 * NC2 * 2);
  ushort* w2_b = (ushort*)alloc((size_t)NC * NC2 * 2);
  ushort* iqT   = (ushort*)alloc(TND * 2 * 3);  // iqT|kT|vT contiguous [b][n][c]
  ushort* q_nat = (ushort*)alloc(TND * 2 * 3);  // q|k|v nat contiguous [b][c][n]
  ushort* qt    = (ushort*)alloc(TND * 2 * 2);  // qt|kt contiguous [(b h)][n][d]
  ushort* xT    = (ushort*)alloc(TND * 2);      // attn@V, [b][n][h*64+d]
  ushort* xmT   = (ushort*)alloc(TND * 2);      // merge out^T [b][n][co]
  ushort* hT    = (ushort*)alloc((size_t)NB * NN * NC2 * 2);
  float*  stats = (float*)alloc(NC2 * 2 * 4);
  float4* aff   = (float4*)alloc(NC2 * 16);
  ushort* kT    = iqT + TND;
  ushort* vT    = iqT + 2 * TND;
  ushort* v_nat = q_nat + 2 * TND;
  ushort* kt    = qt + TND;

  hipMemsetAsync(stats, 0, NC2 * 2 * 4, stream);

  k_cast3<<<dim3(256, 3), 256, 0, stream>>>(Wq, Wk, Wv, wq_b);
  k_cast_wm_perm<<<dim3(256), 256, 0, stream>>>(Wm, wm_b);
  k_cast<<<dim3(1024), 256, 0, stream>>>(W1, w1_b, NC2 * NC2);
  k_cast<<<dim3(512), 256, 0, stream>>>(W2, w2_b, NC * NC2);

  k_tc3<<<dim3(8, 32, 24), 256, 0, stream>>>(iq, keyi, vali, iqT);

  k_gemm<M_PROJ><<<dim3(16, 2, 24), 256, 0, stream>>>(wq_b, nullptr, iqT, bq, bk, bv, nullptr, nullptr, nullptr, q_nat);

  k_ht2<<<dim3(8, 8, 64), 256, 0, stream>>>(q_nat, qt);

  k_attn<<<dim3(1024), 256, 0, stream>>>(qt, kt, v_nat, attn, xT);

  k_gemm<M_WM><<<dim3(2, 32, 8), 256, 0, stream>>>(xT, nullptr, wm_b, bm, nullptr, nullptr, nullptr, nullptr, nullptr, xmT);

  k_gemm<M_W1><<<dim3(4, 16, 8), 256, 0, stream>>>(xmT, iqT, w1_b, b1, nullptr, nullptr, nullptr, stats, nullptr, hT);

  k_bn_finalize<<<dim3(2), 256, 0, stream>>>(stats, gamma, beta, aff);

  k_gemm<M_W2><<<dim3(16, 4, 8), 256, 0, stream>>>(w2_b, nullptr, hT, b2, nullptr, nullptr, aff, nullptr, out, nullptr);
}